// Round 2
// baseline (916.803 us; speedup 1.0000x reference)
//
#include <hip/hip_runtime.h>
#include <math.h>

#define N_ELEC 4096
#define DMODEL 512
#define NHEADS 8
#define DK 64

// acc[4][4] += outer(a, b) where a,b are float4
#define OUTER4(acc, a, b) do { \
  acc[0][0] += a.x*b.x; acc[0][1] += a.x*b.y; acc[0][2] += a.x*b.z; acc[0][3] += a.x*b.w; \
  acc[1][0] += a.y*b.x; acc[1][1] += a.y*b.y; acc[1][2] += a.y*b.z; acc[1][3] += a.y*b.w; \
  acc[2][0] += a.z*b.x; acc[2][1] += a.z*b.y; acc[2][2] += a.z*b.z; acc[2][3] += a.z*b.w; \
  acc[3][0] += a.w*b.x; acc[3][1] += a.w*b.y; acc[3][2] += a.w*b.z; acc[3][3] += a.w*b.w; \
} while (0)

// C[64x64 tile] = A[.,K] @ W[K, colOff + .] + bias ; optional head-major scatter
// headMajor: C index = h*(N_ELEC*DK) + row*DK + d  with h=col/64, d=col%64
__global__ __launch_bounds__(256) void gemm64(
    const float* __restrict__ A, int lda,
    const float* __restrict__ W, int ldw, int wColOff,
    const float* __restrict__ bias,
    float* __restrict__ C, int headMajor, int Kdim)
{
  __shared__ float As[16][64];   // [kk][row]  (A tile transposed)
  __shared__ float Ws[16][64];   // [kk][col]
  const int col0 = blockIdx.x * 64;
  const int row0 = blockIdx.y * 64;
  const int t  = threadIdx.x;
  const int tx = t & 15, ty = t >> 4;
  const int arow = t & 63, aslot = t >> 6;     // A staging: 64 rows x 4 float4-slots
  const int wrow = t >> 4, wcol = (t & 15) * 4; // W staging: 16 rows x 16 float4-slots
  float acc[4][4] = {};

  for (int k0 = 0; k0 < Kdim; k0 += 16) {
    float4 av = *(const float4*)&A[(size_t)(row0 + arow) * lda + k0 + aslot * 4];
    float4 wv = *(const float4*)&W[(size_t)(k0 + wrow) * ldw + wColOff + col0 + wcol];
    __syncthreads();            // previous iteration's LDS reads complete
    As[aslot*4+0][arow] = av.x;
    As[aslot*4+1][arow] = av.y;
    As[aslot*4+2][arow] = av.z;
    As[aslot*4+3][arow] = av.w;
    *(float4*)&Ws[wrow][wcol] = wv;
    __syncthreads();
#pragma unroll
    for (int kk = 0; kk < 16; ++kk) {
      float4 a = *(const float4*)&As[kk][ty * 4];
      float4 b = *(const float4*)&Ws[kk][tx * 4];
      OUTER4(acc, a, b);
    }
  }

#pragma unroll
  for (int r = 0; r < 4; ++r) {
    const int row = row0 + ty * 4 + r;
    const int cb  = col0 + tx * 4;
    float4 o;
    o.x = acc[r][0] + bias[cb + 0];
    o.y = acc[r][1] + bias[cb + 1];
    o.z = acc[r][2] + bias[cb + 2];
    o.w = acc[r][3] + bias[cb + 3];
    if (headMajor) {
      const int h = cb >> 6, d = cb & 63;
      *(float4*)&C[(size_t)h * (N_ELEC * DK) + (size_t)row * DK + d] = o;
    } else {
      *(float4*)&C[(size_t)row * DMODEL + cb] = o;
    }
  }
}

// Flash attention, f32. One block = one 64-row Q tile of one head.
// q/k/v buffers are [H][N_ELEC][DK]. Output: vals[N_ELEC][DMODEL] (head-interleaved cols).
__global__ __launch_bounds__(256) void attn64(
    const float* __restrict__ qb, const float* __restrict__ kb,
    const float* __restrict__ vb, float* __restrict__ vals)
{
  const int qt = blockIdx.x, h = blockIdx.y;
  const float* q = qb + (size_t)h * N_ELEC * DK;
  const float* k = kb + (size_t)h * N_ELEC * DK;
  const float* v = vb + (size_t)h * N_ELEC * DK;

  __shared__ float Qs[DK][64];   // [d][i]  (transposed)
  __shared__ float Ks[DK][64];   // [d][j]  (transposed)
  __shared__ float Vs[64][DK];   // [j][c]  column-swizzled by row
  __shared__ float Ps[64][68];   // [j][i]  padded, 16B-aligned rows

  const int t  = threadIdx.x;
  const int tx = t & 15, ty = t >> 4;
  const int arow = t & 63, abase = t >> 6;   // each thread stages 4 float4-slots

  // stage Q tile: 64 rows x 64 cols = 1024 float4 -> 4 per thread
#pragma unroll
  for (int rep = 0; rep < 4; ++rep) {
    const int slot = abase * 4 + rep;        // 0..15
    float4 qv = *(const float4*)&q[(size_t)(qt * 64 + arow) * DK + slot * 4];
    Qs[slot*4+0][arow] = qv.x;
    Qs[slot*4+1][arow] = qv.y;
    Qs[slot*4+2][arow] = qv.z;
    Qs[slot*4+3][arow] = qv.w;
  }

  float m[4], l[4], O[4][4] = {};
#pragma unroll
  for (int r = 0; r < 4; ++r) { m[r] = -INFINITY; l[r] = 0.f; }

  for (int j0 = 0; j0 < N_ELEC; j0 += 64) {
    float4 kv[4], vv[4];
#pragma unroll
    for (int rep = 0; rep < 4; ++rep) {
      const int slot = abase * 4 + rep;
      kv[rep] = *(const float4*)&k[(size_t)(j0 + arow) * DK + slot * 4];
      vv[rep] = *(const float4*)&v[(size_t)(j0 + arow) * DK + slot * 4];
    }
    __syncthreads();            // previous iteration's PV reads complete
#pragma unroll
    for (int rep = 0; rep < 4; ++rep) {
      const int slot = abase * 4 + rep;
      Ks[slot*4+0][arow] = kv[rep].x;
      Ks[slot*4+1][arow] = kv[rep].y;
      Ks[slot*4+2][arow] = kv[rep].z;
      Ks[slot*4+3][arow] = kv[rep].w;
      // swizzle column slot by row so the b128 store isn't bank-aligned
      *(float4*)&Vs[arow][((slot + arow) & 15) * 4] = vv[rep];
    }
    __syncthreads();

    // S = Q @ K^T  (outer product over d)
    float s[4][4] = {};
#pragma unroll
    for (int d = 0; d < DK; ++d) {
      float4 a = *(const float4*)&Qs[d][ty * 4];
      float4 b = *(const float4*)&Ks[d][tx * 4];
      OUTER4(s, a, b);
    }

    // online softmax (rows ty*4+r; 16 tx-lanes per row group)
#pragma unroll
    for (int r = 0; r < 4; ++r) {
#pragma unroll
      for (int c = 0; c < 4; ++c) s[r][c] *= 0.125f;   // 1/sqrt(64)
      float rm = fmaxf(fmaxf(s[r][0], s[r][1]), fmaxf(s[r][2], s[r][3]));
#pragma unroll
      for (int off = 1; off < 16; off <<= 1)
        rm = fmaxf(rm, __shfl_xor(rm, off));
      const float mnew = fmaxf(m[r], rm);
      const float corr = __expf(m[r] - mnew);
      float rs = 0.f;
#pragma unroll
      for (int c = 0; c < 4; ++c) { s[r][c] = __expf(s[r][c] - mnew); rs += s[r][c]; }
#pragma unroll
      for (int off = 1; off < 16; off <<= 1)
        rs += __shfl_xor(rs, off);
      l[r] = l[r] * corr + rs;
      m[r] = mnew;
#pragma unroll
      for (int c = 0; c < 4; ++c) O[r][c] *= corr;
    }

    // P -> LDS (transposed)
#pragma unroll
    for (int r = 0; r < 4; ++r)
#pragma unroll
      for (int c = 0; c < 4; ++c)
        Ps[tx * 4 + c][ty * 4 + r] = s[r][c];
    __syncthreads();

    // O += P @ V  (outer product over j)
#pragma unroll
    for (int j = 0; j < 64; ++j) {
      float4 a = *(const float4*)&Ps[j][ty * 4];
      float4 b = *(const float4*)&Vs[j][((tx + j) & 15) * 4];
      OUTER4(O, a, b);
    }
  }

#pragma unroll
  for (int r = 0; r < 4; ++r) {
    const float inv = 1.f / l[r];
    float4 o;
    o.x = O[r][0] * inv; o.y = O[r][1] * inv;
    o.z = O[r][2] * inv; o.w = O[r][3] * inv;
    const int row = qt * 64 + ty * 4 + r;
    *(float4*)&vals[(size_t)row * DMODEL + h * DK + tx * 4] = o;
  }
}

extern "C" void kernel_launch(void* const* d_in, const int* in_sizes, int n_in,
                              void* d_out, int out_size, void* d_ws, size_t ws_size,
                              hipStream_t stream) {
  const float* hs   = (const float*)d_in[0];
  const float* hd   = (const float*)d_in[1];
  const float* qk_w = (const float*)d_in[2];
  const float* qk_b = (const float*)d_in[3];
  const float* v_w  = (const float*)d_in[4];
  const float* v_b  = (const float*)d_in[5];
  const float* o_w  = (const float*)d_in[6];
  const float* o_b  = (const float*)d_in[7];
  float* out = (float*)d_out;

  // workspace layout (f32): q,k,v head-major [8][4096][64] + vals [4096][512] = 32 MB
  float* ws   = (float*)d_ws;
  float* qbuf = ws;
  float* kbuf = ws + (size_t)NHEADS * N_ELEC * DK;       // +2M floats
  float* vbuf = ws + 2 * (size_t)NHEADS * N_ELEC * DK;   // +4M
  float* vals = ws + 3 * (size_t)NHEADS * N_ELEC * DK;   // +6M

  dim3 blk(256);
  // projections: q, k (from hs @ qk_kernel), v (from hd @ v_kernel) -> head-major
  gemm64<<<dim3(8, 64), blk, 0, stream>>>(hs, 512, qk_w, 1024,   0, qk_b,       qbuf, 1, 512);
  gemm64<<<dim3(8, 64), blk, 0, stream>>>(hs, 512, qk_w, 1024, 512, qk_b + 512, kbuf, 1, 512);
  gemm64<<<dim3(8, 64), blk, 0, stream>>>(hd, 512, v_w,   512,   0, v_b,        vbuf, 1, 512);
  // flash attention per head
  attn64<<<dim3(64, 8), blk, 0, stream>>>(qbuf, kbuf, vbuf, vals);
  // output projection
  gemm64<<<dim3(8, 64), blk, 0, stream>>>(vals, 512, o_w, 512, 0, o_b, out, 0, 512);
}

// Round 3
// 150.928 us; speedup vs baseline: 6.0744x; 6.0744x over previous
//
#include <hip/hip_runtime.h>
#include <math.h>

#define N_ELEC 4096
#define DMODEL 512
#define NHEADS 8
#define DK 64

typedef __attribute__((ext_vector_type(8))) short  bf16x8;
typedef __attribute__((ext_vector_type(4))) float  f32x4;
typedef __attribute__((ext_vector_type(8))) ushort u16x8;
typedef __attribute__((ext_vector_type(4))) ushort u16x4;

// XOR-swizzle for [R][64] bf16 tiles (row stride 128B): spreads the 16-row
// column-read across 8 16B slots -> 2-way (free) instead of 16-way conflicts.
__device__ __forceinline__ int swz(int r, int c) { return r * 64 + (c ^ ((r & 7) * 8)); }

__device__ __forceinline__ ushort f2bf(float f) {
  union { float f; unsigned int u; } cv; cv.f = f;
  unsigned int u = cv.u;
  u += 0x7FFFu + ((u >> 16) & 1u);   // RNE
  return (ushort)(u >> 16);
}

// ---------- prep: f32 -> bf16 elementwise ----------
__global__ __launch_bounds__(256) void conv_h(const float* __restrict__ in, ushort* __restrict__ out) {
  const int idx = (blockIdx.x * 256 + threadIdx.x) * 8;
  float4 a = *(const float4*)(in + idx);
  float4 b = *(const float4*)(in + idx + 4);
  u16x8 o;
  o[0] = f2bf(a.x); o[1] = f2bf(a.y); o[2] = f2bf(a.z); o[3] = f2bf(a.w);
  o[4] = f2bf(b.x); o[5] = f2bf(b.y); o[6] = f2bf(b.z); o[7] = f2bf(b.w);
  *(u16x8*)(out + idx) = o;
}

// ---------- prep: f32 [R][C] -> bf16 transposed [C][R] ----------
__global__ __launch_bounds__(256) void transpose_w(const float* __restrict__ in, ushort* __restrict__ out,
                                                   int R, int C) {
  __shared__ float Ts[64][68];
  const int ct = blockIdx.x * 64, rt = blockIdx.y * 64;
  const int t = threadIdx.x;
  const int lr = t >> 4, lc4 = (t & 15) * 4;
#pragma unroll
  for (int rep = 0; rep < 4; ++rep) {
    const int r = lr + rep * 16;
    float4 v = *(const float4*)(in + (size_t)(rt + r) * C + ct + lc4);
    Ts[r][lc4] = v.x; Ts[r][lc4 + 1] = v.y; Ts[r][lc4 + 2] = v.z; Ts[r][lc4 + 3] = v.w;
  }
  __syncthreads();
#pragma unroll
  for (int rep = 0; rep < 4; ++rep) {
    const int c = lr + rep * 16;   // out row (= original col)
    u16x4 o;
    o[0] = f2bf(Ts[lc4 + 0][c]); o[1] = f2bf(Ts[lc4 + 1][c]);
    o[2] = f2bf(Ts[lc4 + 2][c]); o[3] = f2bf(Ts[lc4 + 3][c]);
    *(u16x4*)(out + (size_t)(ct + c) * R + rt + lc4) = o;
  }
}

// ---------- projection GEMM, bf16 MFMA ----------
// MODE 0: QK proj (swapped orient) -> bf16 head-major [h][N][64]
// MODE 1: V  proj (normal orient)  -> bf16 transposed [h][64][N]
// MODE 2: out proj (swapped)       -> f32 [N][512] + bias
template<int MODE>
__global__ __launch_bounds__(256) void proj(
    const ushort* __restrict__ Wt,   // [n][512] bf16 (transposed weights)
    const ushort* __restrict__ Act,  // [4096][512] bf16
    const float*  __restrict__ bias,
    void* __restrict__ outp)
{
  __shared__ ushort hss[64 * 64];
  __shared__ ushort wts[64 * 64];
  const int mt64 = blockIdx.x, nt64 = blockIdx.y;
  const int t = threadIdx.x, w = t >> 6, lane = t & 63;
  const int r = lane, fr = lane & 15, fp = lane >> 4;

  const ushort* aRow = Act + (size_t)(mt64 * 64 + r) * 512;
  const ushort* wRow = Wt  + (size_t)(nt64 * 64 + r) * 512;

  u16x8 ha[2], wa[2];
#pragma unroll
  for (int rep = 0; rep < 2; ++rep) {
    ha[rep] = *(const u16x8*)(aRow + (w + rep * 4) * 8);
    wa[rep] = *(const u16x8*)(wRow + (w + rep * 4) * 8);
  }

  f32x4 acc[4] = {{0.f,0.f,0.f,0.f},{0.f,0.f,0.f,0.f},{0.f,0.f,0.f,0.f},{0.f,0.f,0.f,0.f}};

  for (int k0 = 0; k0 < 512; k0 += 64) {
    __syncthreads();
#pragma unroll
    for (int rep = 0; rep < 2; ++rep) {
      *(u16x8*)&hss[swz(r, (w + rep * 4) * 8)] = ha[rep];
      *(u16x8*)&wts[swz(r, (w + rep * 4) * 8)] = wa[rep];
    }
    __syncthreads();
    if (k0 + 64 < 512) {
#pragma unroll
      for (int rep = 0; rep < 2; ++rep) {
        ha[rep] = *(const u16x8*)(aRow + k0 + 64 + (w + rep * 4) * 8);
        wa[rep] = *(const u16x8*)(wRow + k0 + 64 + (w + rep * 4) * 8);
      }
    }
    const ushort* invT = (MODE == 1) ? hss : wts;  // mfma A operand (wave-invariant rows)
    const ushort* varT = (MODE == 1) ? wts : hss;  // mfma B operand (4 tiles)
#pragma unroll
    for (int kh = 0; kh < 2; ++kh) {
      bf16x8 ia = *(const bf16x8*)&invT[swz(w * 16 + fr, fp * 8 + kh * 32)];
#pragma unroll
      for (int i = 0; i < 4; ++i) {
        bf16x8 vb = *(const bf16x8*)&varT[swz(i * 16 + fr, fp * 8 + kh * 32)];
        acc[i] = __builtin_amdgcn_mfma_f32_16x16x32_bf16(ia, vb, acc[i], 0, 0, 0);
      }
    }
  }

  if (MODE == 0) {
    // C^T: row n = nt64*64 + w*16 + fp*4 + g, col m = mt64*64 + i*16 + fr
    ushort* out = (ushort*)outp;
    const int dq = w * 16 + fp * 4;
    float b4[4];
#pragma unroll
    for (int g = 0; g < 4; ++g) b4[g] = bias[nt64 * 64 + dq + g];
#pragma unroll
    for (int i = 0; i < 4; ++i) {
      const int m = mt64 * 64 + i * 16 + fr;
      u16x4 o;
#pragma unroll
      for (int g = 0; g < 4; ++g) o[g] = f2bf(acc[i][g] + b4[g]);
      *(u16x4*)(out + (size_t)nt64 * N_ELEC * DK + (size_t)m * DK + dq) = o;
    }
  } else if (MODE == 1) {
    // C: row m = mt64*64 + w*16 + fp*4 + g, col n = nt64*64 + i*16 + fr
    ushort* out = (ushort*)outp;
    const int m0 = mt64 * 64 + w * 16 + fp * 4;
#pragma unroll
    for (int i = 0; i < 4; ++i) {
      const int n = nt64 * 64 + i * 16 + fr;
      const float bb = bias[n];
      u16x4 o;
#pragma unroll
      for (int g = 0; g < 4; ++g) o[g] = f2bf(acc[i][g] + bb);
      *(u16x4*)(out + (size_t)nt64 * DK * N_ELEC + (size_t)(i * 16 + fr) * N_ELEC + m0) = o;
    }
  } else {
    // C^T -> f32 out[m][n]
    float* out = (float*)outp;
    const int n0 = nt64 * 64 + w * 16 + fp * 4;
    float4 bb = *(const float4*)(bias + n0);
#pragma unroll
    for (int i = 0; i < 4; ++i) {
      const int m = mt64 * 64 + i * 16 + fr;
      float4 o;
      o.x = acc[i][0] + bb.x; o.y = acc[i][1] + bb.y;
      o.z = acc[i][2] + bb.z; o.w = acc[i][3] + bb.w;
      *(float4*)(out + (size_t)m * DMODEL + n0) = o;
    }
  }
}

// ---------- flash attention, bf16 MFMA, swapped-QK^T ----------
// qb/kb: [h][4096][64] bf16, vtb: [h][64][4096] bf16, vals: [4096][512] bf16
__global__ __launch_bounds__(256) void attn(
    const ushort* __restrict__ qb, const ushort* __restrict__ kb,
    const ushort* __restrict__ vtb, ushort* __restrict__ vals)
{
  __shared__ ushort Qs[64 * 64], Ks[64 * 64], Vts[64 * 64];
  __shared__ ushort Ps[4][16 * 64];
  const int bid = blockIdx.x;
  const int h = bid & 7, qt = bid >> 3;        // head-chunked: XCD i holds head i's K/V in L2
  const int t = threadIdx.x, w = t >> 6, lane = t & 63;
  const int r = lane, fr = lane & 15, fp = lane >> 4;

  const ushort* q  = qb  + (size_t)h * N_ELEC * DK + (size_t)qt * 64 * DK;
  const ushort* k  = kb  + (size_t)h * N_ELEC * DK;
  const ushort* vt = vtb + (size_t)h * DK * N_ELEC;

  // stage Q once
#pragma unroll
  for (int rep = 0; rep < 2; ++rep) {
    u16x8 qv = *(const u16x8*)(q + r * DK + (w + rep * 4) * 8);
    *(u16x8*)&Qs[swz(r, (w + rep * 4) * 8)] = qv;
  }
  // prefetch KV tile 0
  u16x8 kreg[2], vreg[2];
#pragma unroll
  for (int rep = 0; rep < 2; ++rep) {
    kreg[rep] = *(const u16x8*)(k  + (size_t)r * DK + (w + rep * 4) * 8);
    vreg[rep] = *(const u16x8*)(vt + (size_t)r * N_ELEC + (w + rep * 4) * 8);
  }
  __syncthreads();
  // Q fragments (invariant across the KV loop)
  bf16x8 qf0 = *(const bf16x8*)&Qs[swz(w * 16 + fr, fp * 8)];
  bf16x8 qf1 = *(const bf16x8*)&Qs[swz(w * 16 + fr, fp * 8 + 32)];

  float mrun = -INFINITY, lsum = 0.f;
  f32x4 oacc[4] = {{0.f,0.f,0.f,0.f},{0.f,0.f,0.f,0.f},{0.f,0.f,0.f,0.f},{0.f,0.f,0.f,0.f}};

  for (int j0 = 0; j0 < N_ELEC; j0 += 64) {
    __syncthreads();   // previous iteration's K/V reads (and pre-loop qf reads) done
#pragma unroll
    for (int rep = 0; rep < 2; ++rep) {
      *(u16x8*)&Ks[swz(r, (w + rep * 4) * 8)]  = kreg[rep];
      *(u16x8*)&Vts[swz(r, (w + rep * 4) * 8)] = vreg[rep];
    }
    __syncthreads();
    if (j0 + 64 < N_ELEC) {
      const int jn = j0 + 64;
#pragma unroll
      for (int rep = 0; rep < 2; ++rep) {
        kreg[rep] = *(const u16x8*)(k  + (size_t)(jn + r) * DK + (w + rep * 4) * 8);
        vreg[rep] = *(const u16x8*)(vt + (size_t)r * N_ELEC + jn + (w + rep * 4) * 8);
      }
    }
    // S^T = K @ Q^T  (lane: k-rows = kt*16 + fp*4 + g, q-col = w*16 + fr)
    f32x4 sacc[4] = {{0.f,0.f,0.f,0.f},{0.f,0.f,0.f,0.f},{0.f,0.f,0.f,0.f},{0.f,0.f,0.f,0.f}};
#pragma unroll
    for (int kt = 0; kt < 4; ++kt) {
      bf16x8 a0 = *(const bf16x8*)&Ks[swz(kt * 16 + fr, fp * 8)];
      bf16x8 a1 = *(const bf16x8*)&Ks[swz(kt * 16 + fr, fp * 8 + 32)];
      sacc[kt] = __builtin_amdgcn_mfma_f32_16x16x32_bf16(a0, qf0, sacc[kt], 0, 0, 0);
      sacc[kt] = __builtin_amdgcn_mfma_f32_16x16x32_bf16(a1, qf1, sacc[kt], 0, 0, 0);
    }
    // online softmax: per-lane column q, 16 k-values in regs + xor16/32 across k-quarters
    float pv[16];
    float pm = -INFINITY;
#pragma unroll
    for (int kt = 0; kt < 4; ++kt)
#pragma unroll
      for (int g = 0; g < 4; ++g) {
        const float x = sacc[kt][g] * 0.125f;
        pv[kt * 4 + g] = x;
        pm = fmaxf(pm, x);
      }
    pm = fmaxf(pm, __shfl_xor(pm, 16));
    pm = fmaxf(pm, __shfl_xor(pm, 32));
    const float mnew = fmaxf(mrun, pm);
    const float corr = __expf(mrun - mnew);
    mrun = mnew;
    float rs = 0.f;
#pragma unroll
    for (int i = 0; i < 16; ++i) { pv[i] = __expf(pv[i] - mnew); rs += pv[i]; }
    rs += __shfl_xor(rs, 16);
    rs += __shfl_xor(rs, 32);
    lsum = lsum * corr + rs;
#pragma unroll
    for (int dt = 0; dt < 4; ++dt) {
      oacc[dt][0] *= corr; oacc[dt][1] *= corr; oacc[dt][2] *= corr; oacc[dt][3] *= corr;
    }
    // P -> per-wave LDS (row-major [16 q][64 k], swizzled)
#pragma unroll
    for (int kt = 0; kt < 4; ++kt) {
      u16x4 pk;
#pragma unroll
      for (int g = 0; g < 4; ++g) pk[g] = f2bf(pv[kt * 4 + g]);
      *(u16x4*)&Ps[w][swz(fr, kt * 16 + fp * 4)] = pk;
    }
    asm volatile("s_waitcnt lgkmcnt(0)" ::: "memory");  // intra-wave cross-lane P RAW
    // O^T += V^T @ P^T
    bf16x8 pf0 = *(const bf16x8*)&Ps[w][swz(fr, fp * 8)];
    bf16x8 pf1 = *(const bf16x8*)&Ps[w][swz(fr, fp * 8 + 32)];
#pragma unroll
    for (int dt = 0; dt < 4; ++dt) {
      bf16x8 v0 = *(const bf16x8*)&Vts[swz(dt * 16 + fr, fp * 8)];
      bf16x8 v1 = *(const bf16x8*)&Vts[swz(dt * 16 + fr, fp * 8 + 32)];
      oacc[dt] = __builtin_amdgcn_mfma_f32_16x16x32_bf16(v0, pf0, oacc[dt], 0, 0, 0);
      oacc[dt] = __builtin_amdgcn_mfma_f32_16x16x32_bf16(v1, pf1, oacc[dt], 0, 0, 0);
    }
  }
  // epilogue: lane holds O^T[d = dt*16 + fp*4 + g][q = w*16 + fr]
  const float inv = 1.f / lsum;
  const int qrow = qt * 64 + w * 16 + fr;
#pragma unroll
  for (int dt = 0; dt < 4; ++dt) {
    u16x4 o;
#pragma unroll
    for (int g = 0; g < 4; ++g) o[g] = f2bf(oacc[dt][g] * inv);
    *(u16x4*)(vals + (size_t)qrow * DMODEL + h * DK + dt * 16 + fp * 4) = o;
  }
}

extern "C" void kernel_launch(void* const* d_in, const int* in_sizes, int n_in,
                              void* d_out, int out_size, void* d_ws, size_t ws_size,
                              hipStream_t stream) {
  const float* hs   = (const float*)d_in[0];
  const float* hd   = (const float*)d_in[1];
  const float* qk_w = (const float*)d_in[2];
  const float* qk_b = (const float*)d_in[3];
  const float* v_w  = (const float*)d_in[4];
  const float* v_b  = (const float*)d_in[5];
  const float* o_w  = (const float*)d_in[6];
  const float* o_b  = (const float*)d_in[7];
  float* out = (float*)d_out;

  // ws layout (bf16 elements)
  ushort* ws    = (ushort*)d_ws;
  ushort* hsb   = ws;                                  // [4096][512]
  ushort* hdb   = hsb  + (size_t)N_ELEC * DMODEL;      // [4096][512]
  ushort* wqkT  = hdb  + (size_t)N_ELEC * DMODEL;      // [1024][512]
  ushort* wvT   = wqkT + (size_t)1024 * 512;           // [512][512]
  ushort* woT   = wvT  + (size_t)512 * 512;            // [512][512]
  ushort* qbuf  = woT  + (size_t)512 * 512;            // [8][4096][64]
  ushort* kbuf  = qbuf + (size_t)NHEADS * N_ELEC * DK; // [8][4096][64]
  ushort* vbufT = kbuf + (size_t)NHEADS * N_ELEC * DK; // [8][64][4096]
  ushort* valsb = vbufT + (size_t)NHEADS * DK * N_ELEC;// [4096][512]

  dim3 blk(256);
  conv_h<<<dim3(N_ELEC * DMODEL / 2048), blk, 0, stream>>>(hs, hsb);
  conv_h<<<dim3(N_ELEC * DMODEL / 2048), blk, 0, stream>>>(hd, hdb);
  transpose_w<<<dim3(16, 8), blk, 0, stream>>>(qk_w, wqkT, 512, 1024);
  transpose_w<<<dim3(8, 8),  blk, 0, stream>>>(v_w,  wvT,  512, 512);
  transpose_w<<<dim3(8, 8),  blk, 0, stream>>>(o_w,  woT,  512, 512);

  proj<0><<<dim3(64, 8), blk, 0, stream>>>(wqkT,             hsb,   qk_b,       qbuf);
  proj<0><<<dim3(64, 8), blk, 0, stream>>>(wqkT + 512 * 512, hsb,   qk_b + 512, kbuf);
  proj<1><<<dim3(64, 8), blk, 0, stream>>>(wvT,              hdb,   v_b,        vbufT);

  attn<<<dim3(512), blk, 0, stream>>>(qbuf, kbuf, vbufT, valsb);

  proj<2><<<dim3(64, 8), blk, 0, stream>>>(woT, valsb, o_b, out);
}

// Round 5
// 135.353 us; speedup vs baseline: 6.7734x; 1.1151x over previous
//
#include <hip/hip_runtime.h>
#include <math.h>

#define N_ELEC 4096
#define DMODEL 512
#define NHEADS 8
#define DK 64

typedef __attribute__((ext_vector_type(8))) short  bf16x8;
typedef __attribute__((ext_vector_type(4))) float  f32x4;
typedef __attribute__((ext_vector_type(8))) ushort u16x8;
typedef __attribute__((ext_vector_type(4))) ushort u16x4;
typedef __attribute__((ext_vector_type(2))) unsigned int u32x2;

// XOR-swizzle for [R][64] bf16 tiles (row stride 128B)
__device__ __forceinline__ int swz(int r, int c) { return r * 64 + (c ^ ((r & 7) * 8)); }

__device__ __forceinline__ ushort f2bf(float f) {
  union { float f; unsigned int u; } cv; cv.f = f;
  unsigned int u = cv.u;
  u += 0x7FFFu + ((u >> 16) & 1u);   // RNE
  return (ushort)(u >> 16);
}

__device__ __forceinline__ unsigned cvtpk(float lo, float hi) {
  unsigned r;
  asm("v_cvt_pk_bf16_f32 %0, %1, %2" : "=v"(r) : "v"(lo), "v"(hi));
  return r;
}

#define QK_LOG2E 0.18033688f   // 0.125 * log2(e), folded into q at projection time

// ---------- fused prep: f32->bf16 conv of hs/hd + 3 weight transposes ----------
__global__ __launch_bounds__(256) void prep(
    const float* __restrict__ hs, const float* __restrict__ hd,
    const float* __restrict__ qk_w, const float* __restrict__ v_w, const float* __restrict__ o_w,
    ushort* __restrict__ hsb, ushort* __restrict__ hdb,
    ushort* __restrict__ wqkT, ushort* __restrict__ wvT, ushort* __restrict__ woT)
{
  __shared__ float Ts[64][68];
  const int b = blockIdx.x, t = threadIdx.x;
  if (b < 2048) {
    const float* in = (b < 1024) ? hs : hd;
    ushort* outp = (b < 1024) ? hsb : hdb;
    const int idx = ((b & 1023) * 256 + t) * 8;
    float4 a = *(const float4*)(in + idx);
    float4 b2 = *(const float4*)(in + idx + 4);
    u16x8 o;
    o[0] = f2bf(a.x); o[1] = f2bf(a.y); o[2] = f2bf(a.z); o[3] = f2bf(a.w);
    o[4] = f2bf(b2.x); o[5] = f2bf(b2.y); o[6] = f2bf(b2.z); o[7] = f2bf(b2.w);
    *(u16x8*)(outp + idx) = o;
    return;
  }
  const float* in; ushort* outp; int C, tb;
  if (b < 2176)      { in = qk_w; outp = wqkT; C = 1024; tb = b - 2048; }
  else if (b < 2240) { in = v_w;  outp = wvT;  C = 512;  tb = b - 2176; }
  else               { in = o_w;  outp = woT;  C = 512;  tb = b - 2240; }
  const int ctiles = C >> 6;
  const int ct = (tb % ctiles) * 64, rt = (tb / ctiles) * 64;
  const int lr = t >> 4, lc4 = (t & 15) * 4;
#pragma unroll
  for (int rep = 0; rep < 4; ++rep) {
    const int r = lr + rep * 16;
    float4 v = *(const float4*)(in + (size_t)(rt + r) * C + ct + lc4);
    Ts[r][lc4] = v.x; Ts[r][lc4 + 1] = v.y; Ts[r][lc4 + 2] = v.z; Ts[r][lc4 + 3] = v.w;
  }
  __syncthreads();
#pragma unroll
  for (int rep = 0; rep < 4; ++rep) {
    const int c = lr + rep * 16;
    u16x4 o;
    o[0] = f2bf(Ts[lc4 + 0][c]); o[1] = f2bf(Ts[lc4 + 1][c]);
    o[2] = f2bf(Ts[lc4 + 2][c]); o[3] = f2bf(Ts[lc4 + 3][c]);
    *(u16x4*)(outp + (size_t)(ct + c) * 512 + rt + lc4) = o;
  }
}

// ---------- projection GEMM, bf16 MFMA 16x16x32 (round-3 validated) ----------
// MODE 0: QK proj -> bf16 head-major [h][N][64] (q half pre-scaled by QK_LOG2E)
// MODE 1: V  proj -> bf16 transposed [h][64][N]
// MODE 2: out proj -> f32 [N][512] + bias
template<int MODE>
__global__ __launch_bounds__(256) void proj(
    const ushort* __restrict__ Wt, const ushort* __restrict__ Act,
    const float* __restrict__ bias, void* __restrict__ outp)
{
  __shared__ ushort hss[64 * 64];
  __shared__ ushort wts[64 * 64];
  const int mt64 = blockIdx.x, nt64 = blockIdx.y;
  const int t = threadIdx.x, w = t >> 6, lane = t & 63;
  const int r = lane, fr = lane & 15, fp = lane >> 4;

  const ushort* aRow = Act + (size_t)(mt64 * 64 + r) * 512;
  const ushort* wRow = Wt  + (size_t)(nt64 * 64 + r) * 512;

  u16x8 ha[2], wa[2];
#pragma unroll
  for (int rep = 0; rep < 2; ++rep) {
    ha[rep] = *(const u16x8*)(aRow + (w + rep * 4) * 8);
    wa[rep] = *(const u16x8*)(wRow + (w + rep * 4) * 8);
  }

  f32x4 acc[4] = {{0.f,0.f,0.f,0.f},{0.f,0.f,0.f,0.f},{0.f,0.f,0.f,0.f},{0.f,0.f,0.f,0.f}};

  for (int k0 = 0; k0 < 512; k0 += 64) {
    __syncthreads();
#pragma unroll
    for (int rep = 0; rep < 2; ++rep) {
      *(u16x8*)&hss[swz(r, (w + rep * 4) * 8)] = ha[rep];
      *(u16x8*)&wts[swz(r, (w + rep * 4) * 8)] = wa[rep];
    }
    __syncthreads();
    if (k0 + 64 < 512) {
#pragma unroll
      for (int rep = 0; rep < 2; ++rep) {
        ha[rep] = *(const u16x8*)(aRow + k0 + 64 + (w + rep * 4) * 8);
        wa[rep] = *(const u16x8*)(wRow + k0 + 64 + (w + rep * 4) * 8);
      }
    }
    const ushort* invT = (MODE == 1) ? hss : wts;
    const ushort* varT = (MODE == 1) ? wts : hss;
#pragma unroll
    for (int kh = 0; kh < 2; ++kh) {
      bf16x8 ia = *(const bf16x8*)&invT[swz(w * 16 + fr, fp * 8 + kh * 32)];
#pragma unroll
      for (int i = 0; i < 4; ++i) {
        bf16x8 vb = *(const bf16x8*)&varT[swz(i * 16 + fr, fp * 8 + kh * 32)];
        acc[i] = __builtin_amdgcn_mfma_f32_16x16x32_bf16(ia, vb, acc[i], 0, 0, 0);
      }
    }
  }

  if (MODE == 0) {
    ushort* out = (ushort*)outp;
    const int dq = w * 16 + fp * 4;
    const float scale = (nt64 < 8) ? QK_LOG2E : 1.0f;   // q half carries softmax scale
    float b4[4];
#pragma unroll
    for (int g = 0; g < 4; ++g) b4[g] = bias[nt64 * 64 + dq + g];
#pragma unroll
    for (int i = 0; i < 4; ++i) {
      const int m = mt64 * 64 + i * 16 + fr;
      u16x4 o;
#pragma unroll
      for (int g = 0; g < 4; ++g) o[g] = f2bf((acc[i][g] + b4[g]) * scale);
      *(u16x4*)(out + (size_t)nt64 * N_ELEC * DK + (size_t)m * DK + dq) = o;
    }
  } else if (MODE == 1) {
    ushort* out = (ushort*)outp;
    const int m0 = mt64 * 64 + w * 16 + fp * 4;
#pragma unroll
    for (int i = 0; i < 4; ++i) {
      const int n = nt64 * 64 + i * 16 + fr;
      const float bb = bias[n];
      u16x4 o;
#pragma unroll
      for (int g = 0; g < 4; ++g) o[g] = f2bf(acc[i][g] + bb);
      *(u16x4*)(out + (size_t)nt64 * DK * N_ELEC + (size_t)(i * 16 + fr) * N_ELEC + m0) = o;
    }
  } else {
    float* out = (float*)outp;
    const int n0 = nt64 * 64 + w * 16 + fp * 4;
    float4 bb = *(const float4*)(bias + n0);
#pragma unroll
    for (int i = 0; i < 4; ++i) {
      const int m = mt64 * 64 + i * 16 + fr;
      float4 o;
      o.x = acc[i][0] + bb.x; o.y = acc[i][1] + bb.y;
      o.z = acc[i][2] + bb.z; o.w = acc[i][3] + bb.w;
      *(float4*)(out + (size_t)m * DMODEL + n0) = o;
    }
  }
}

// ---------- flash attention (round-3 validated compute structure) ----------
// qb/kb: [h][4096][64] bf16 (q pre-scaled to exp2 domain), vtb: [h][64][4096] bf16.
// SPLIT==1: normalized bf16 vals [4096][512]. SPLIT==2: f32 partials + (m,l).
template<int SPLIT>
__global__ __launch_bounds__(256) void attn(
    const ushort* __restrict__ qb, const ushort* __restrict__ kb,
    const ushort* __restrict__ vtb, ushort* __restrict__ vals,
    float* __restrict__ Opart, float2* __restrict__ ML)
{
  __shared__ ushort Ks[64 * 64], Vts[64 * 64];
  __shared__ ushort Ps[4][16 * 64];
  const int bid = blockIdx.x;
  const int h = bid & 7, qt = (bid >> 3) & 63, s = bid >> 9;
  const int t = threadIdx.x, w = t >> 6, lane = t & 63;
  const int r = lane, fr = lane & 15, fp = lane >> 4;
  const int KCH = N_ELEC / SPLIT, NT = KCH / 64;

  const ushort* k  = kb  + (size_t)h * N_ELEC * DK + (size_t)s * KCH * DK;
  const ushort* vt = vtb + (size_t)h * DK * N_ELEC + (size_t)s * KCH;
  const int q = qt * 64 + w * 16 + fr;

  // Q fragments direct from global (same values the round-3 LDS path produced)
  bf16x8 qf0, qf1;
  {
    const ushort* qrow = qb + (size_t)h * N_ELEC * DK + (size_t)q * DK + fp * 8;
    qf0 = *(const bf16x8*)(qrow);
    qf1 = *(const bf16x8*)(qrow + 32);
  }

  // prefetch KV tile 0
  u16x8 kreg[2], vreg[2];
#pragma unroll
  for (int rep = 0; rep < 2; ++rep) {
    kreg[rep] = *(const u16x8*)(k  + (size_t)r * DK + (w + rep * 4) * 8);
    vreg[rep] = *(const u16x8*)(vt + (size_t)r * N_ELEC + (w + rep * 4) * 8);
  }

  float mrun = -INFINITY, lsum = 0.f;
  f32x4 oacc[4] = {{0.f,0.f,0.f,0.f},{0.f,0.f,0.f,0.f},{0.f,0.f,0.f,0.f},{0.f,0.f,0.f,0.f}};

  for (int j0 = 0; j0 < KCH; j0 += 64) {
    __syncthreads();   // previous iteration's K/V reads done
#pragma unroll
    for (int rep = 0; rep < 2; ++rep) {
      *(u16x8*)&Ks[swz(r, (w + rep * 4) * 8)]  = kreg[rep];
      *(u16x8*)&Vts[swz(r, (w + rep * 4) * 8)] = vreg[rep];
    }
    __syncthreads();
    if (j0 + 64 < KCH) {
      const int jn = j0 + 64;
#pragma unroll
      for (int rep = 0; rep < 2; ++rep) {
        kreg[rep] = *(const u16x8*)(k  + (size_t)(jn + r) * DK + (w + rep * 4) * 8);
        vreg[rep] = *(const u16x8*)(vt + (size_t)r * N_ELEC + jn + (w + rep * 4) * 8);
      }
    }
    // S^T = K @ Q^T  (lane: k-rows = kt*16 + fp*4 + g, q-col = w*16 + fr)
    f32x4 sacc[4] = {{0.f,0.f,0.f,0.f},{0.f,0.f,0.f,0.f},{0.f,0.f,0.f,0.f},{0.f,0.f,0.f,0.f}};
#pragma unroll
    for (int kt = 0; kt < 4; ++kt) {
      bf16x8 a0 = *(const bf16x8*)&Ks[swz(kt * 16 + fr, fp * 8)];
      bf16x8 a1 = *(const bf16x8*)&Ks[swz(kt * 16 + fr, fp * 8 + 32)];
      sacc[kt] = __builtin_amdgcn_mfma_f32_16x16x32_bf16(a0, qf0, sacc[kt], 0, 0, 0);
      sacc[kt] = __builtin_amdgcn_mfma_f32_16x16x32_bf16(a1, qf1, sacc[kt], 0, 0, 0);
    }
    // online softmax in exp2 domain (scale already folded into q)
    float pv[16];
    float pm = -INFINITY;
#pragma unroll
    for (int kt = 0; kt < 4; ++kt)
#pragma unroll
      for (int g = 0; g < 4; ++g) {
        const float x = sacc[kt][g];
        pv[kt * 4 + g] = x;
        pm = fmaxf(pm, x);
      }
    pm = fmaxf(pm, __shfl_xor(pm, 16));
    pm = fmaxf(pm, __shfl_xor(pm, 32));
    if (__any(pm > mrun)) {                 // exact skip: corr==1 otherwise
      const float mnew = fmaxf(mrun, pm);
      const float corr = __builtin_amdgcn_exp2f(mrun - mnew);
      lsum *= corr;
#pragma unroll
      for (int dt = 0; dt < 4; ++dt) {
        oacc[dt][0] *= corr; oacc[dt][1] *= corr; oacc[dt][2] *= corr; oacc[dt][3] *= corr;
      }
      mrun = mnew;
    }
    float rs = 0.f;
#pragma unroll
    for (int i = 0; i < 16; ++i) { pv[i] = __builtin_amdgcn_exp2f(pv[i] - mrun); rs += pv[i]; }
    rs += __shfl_xor(rs, 16);
    rs += __shfl_xor(rs, 32);
    lsum += rs;
    // P -> per-wave LDS (row-major [16 q][64 k], swizzled), packed via cvt_pk
#pragma unroll
    for (int kt = 0; kt < 4; ++kt) {
      u32x2 pw;
      pw[0] = cvtpk(pv[kt * 4 + 0], pv[kt * 4 + 1]);
      pw[1] = cvtpk(pv[kt * 4 + 2], pv[kt * 4 + 3]);
      *(u32x2*)&Ps[w][swz(fr, kt * 16 + fp * 4)] = pw;
    }
    asm volatile("s_waitcnt lgkmcnt(0)" ::: "memory");  // intra-wave cross-lane P RAW
    // O^T += V^T @ P^T
    bf16x8 pf0 = *(const bf16x8*)&Ps[w][swz(fr, fp * 8)];
    bf16x8 pf1 = *(const bf16x8*)&Ps[w][swz(fr, fp * 8 + 32)];
#pragma unroll
    for (int dt = 0; dt < 4; ++dt) {
      bf16x8 v0 = *(const bf16x8*)&Vts[swz(dt * 16 + fr, fp * 8)];
      bf16x8 v1 = *(const bf16x8*)&Vts[swz(dt * 16 + fr, fp * 8 + 32)];
      oacc[dt] = __builtin_amdgcn_mfma_f32_16x16x32_bf16(v0, pf0, oacc[dt], 0, 0, 0);
      oacc[dt] = __builtin_amdgcn_mfma_f32_16x16x32_bf16(v1, pf1, oacc[dt], 0, 0, 0);
    }
  }

  // epilogue: lane holds O^T[d = dt*16 + fp*4 + g][q = qt*64 + w*16 + fr]
  if constexpr (SPLIT == 1) {
    const float inv = 1.f / lsum;
#pragma unroll
    for (int dt = 0; dt < 4; ++dt) {
      u16x4 o;
#pragma unroll
      for (int g = 0; g < 4; ++g) o[g] = f2bf(oacc[dt][g] * inv);
      *(u16x4*)(vals + (size_t)q * DMODEL + h * DK + dt * 16 + fp * 4) = o;
    }
  } else {
    float* ob = Opart + ((size_t)(s * NHEADS + h) * N_ELEC + q) * DK;
#pragma unroll
    for (int dt = 0; dt < 4; ++dt) {
      float4 o;
      o.x = oacc[dt][0]; o.y = oacc[dt][1]; o.z = oacc[dt][2]; o.w = oacc[dt][3];
      *(float4*)(ob + dt * 16 + fp * 4) = o;
    }
    if (fp == 0) ML[(size_t)(s * NHEADS + h) * N_ELEC + q] = make_float2(mrun, lsum);
  }
}

// ---------- combine the 2 KV-splits ----------
__global__ __launch_bounds__(256) void combine(
    const float* __restrict__ Opart, const float2* __restrict__ ML,
    ushort* __restrict__ vals)
{
  const int rid = blockIdx.x * 4 + (threadIdx.x >> 6);  // h*4096 + q
  const int d = threadIdx.x & 63;
  const int hh = rid >> 12, qq = rid & 4095;
  const size_t base = (size_t)rid * DK + d;
  const size_t sstride = (size_t)NHEADS * N_ELEC * DK;
  float2 ml0 = ML[rid], ml1 = ML[(size_t)NHEADS * N_ELEC + rid];
  float o0 = Opart[base], o1 = Opart[sstride + base];
  float m = fmaxf(ml0.x, ml1.x);
  float c0 = __builtin_amdgcn_exp2f(ml0.x - m);
  float c1 = __builtin_amdgcn_exp2f(ml1.x - m);
  float l = c0 * ml0.y + c1 * ml1.y;
  vals[(size_t)qq * DMODEL + hh * DK + d] = f2bf((c0 * o0 + c1 * o1) / l);
}

extern "C" void kernel_launch(void* const* d_in, const int* in_sizes, int n_in,
                              void* d_out, int out_size, void* d_ws, size_t ws_size,
                              hipStream_t stream) {
  const float* hs   = (const float*)d_in[0];
  const float* hd   = (const float*)d_in[1];
  const float* qk_w = (const float*)d_in[2];
  const float* qk_b = (const float*)d_in[3];
  const float* v_w  = (const float*)d_in[4];
  const float* v_b  = (const float*)d_in[5];
  const float* o_w  = (const float*)d_in[6];
  const float* o_b  = (const float*)d_in[7];
  float* out = (float*)d_out;

  ushort* ws    = (ushort*)d_ws;
  ushort* hsb   = ws;                                   // [4096][512]
  ushort* hdb   = hsb  + (size_t)N_ELEC * DMODEL;
  ushort* wqkT  = hdb  + (size_t)N_ELEC * DMODEL;       // [1024][512]
  ushort* wvT   = wqkT + (size_t)1024 * 512;            // [512][512]
  ushort* woT   = wvT  + (size_t)512 * 512;             // [512][512]
  ushort* qbuf  = woT  + (size_t)512 * 512;             // [8][4096][64]
  ushort* kbuf  = qbuf + (size_t)NHEADS * N_ELEC * DK;  // [8][4096][64] (contiguous after qbuf)
  ushort* vbufT = kbuf + (size_t)NHEADS * N_ELEC * DK;  // [8][64][4096]
  ushort* valsb = vbufT + (size_t)NHEADS * DK * N_ELEC; // [4096][512]
  float*  Opart = (float*)(valsb + (size_t)N_ELEC * DMODEL);   // [2][8][4096][64] f32
  float2* ML    = (float2*)(Opart + (size_t)2 * NHEADS * N_ELEC * DK);
  const size_t need = (size_t)((char*)(ML + (size_t)2 * NHEADS * N_ELEC) - (char*)d_ws);
  const bool split2 = ws_size >= need;

  dim3 blk(256);
  prep<<<dim3(2304), blk, 0, stream>>>(hs, hd, qk_w, v_w, o_w, hsb, hdb, wqkT, wvT, woT);
  proj<0><<<dim3(64, 16), blk, 0, stream>>>(wqkT, hsb, qk_b, qbuf);   // q (scaled) + k
  proj<1><<<dim3(64, 8),  blk, 0, stream>>>(wvT,  hdb, v_b,  vbufT);

  if (split2) {
    attn<2><<<dim3(1024), blk, 0, stream>>>(qbuf, kbuf, vbufT, nullptr, Opart, ML);
    combine<<<dim3(NHEADS * N_ELEC / 4), blk, 0, stream>>>(Opart, ML, valsb);
  } else {
    attn<1><<<dim3(512), blk, 0, stream>>>(qbuf, kbuf, vbufT, valsb, nullptr, nullptr);
  }

  proj<2><<<dim3(64, 8), blk, 0, stream>>>(woT, valsb, o_b, out);
}

// Round 6
// 125.047 us; speedup vs baseline: 7.3317x; 1.0824x over previous
//
#include <hip/hip_runtime.h>
#include <math.h>

#define N_ELEC 4096
#define DMODEL 512
#define NHEADS 8
#define DK 64

typedef __attribute__((ext_vector_type(8))) short  bf16x8;
typedef __attribute__((ext_vector_type(4))) float  f32x4;
typedef __attribute__((ext_vector_type(8))) ushort u16x8;
typedef __attribute__((ext_vector_type(4))) ushort u16x4;
typedef __attribute__((ext_vector_type(2))) unsigned int u32x2;

// XOR-swizzle for [R][64] bf16 tiles (row stride 128B)
__device__ __forceinline__ int swz(int r, int c) { return r * 64 + (c ^ ((r & 7) * 8)); }

__device__ __forceinline__ ushort f2bf(float f) {
  union { float f; unsigned int u; } cv; cv.f = f;
  unsigned int u = cv.u;
  u += 0x7FFFu + ((u >> 16) & 1u);   // RNE
  return (ushort)(u >> 16);
}

__device__ __forceinline__ unsigned cvtpk(float lo, float hi) {
  unsigned r;
  asm("v_cvt_pk_bf16_f32 %0, %1, %2" : "=v"(r) : "v"(lo), "v"(hi));
  return r;
}

#define GLL16(gp, lp) __builtin_amdgcn_global_load_lds( \
    (const __attribute__((address_space(1))) void*)(gp), \
    (__attribute__((address_space(3))) void*)(lp), 16, 0, 0)

#define QK_LOG2E 0.18033688f   // 0.125 * log2(e), folded into q at projection time

// ---------- fused prep: f32->bf16 conv of hs/hd + 3 weight transposes ----------
__global__ __launch_bounds__(256) void prep(
    const float* __restrict__ hs, const float* __restrict__ hd,
    const float* __restrict__ qk_w, const float* __restrict__ v_w, const float* __restrict__ o_w,
    ushort* __restrict__ hsb, ushort* __restrict__ hdb,
    ushort* __restrict__ wqkT, ushort* __restrict__ wvT, ushort* __restrict__ woT)
{
  __shared__ float Ts[64][68];
  const int b = blockIdx.x, t = threadIdx.x;
  if (b < 2048) {
    const float* in = (b < 1024) ? hs : hd;
    ushort* outp = (b < 1024) ? hsb : hdb;
    const int idx = ((b & 1023) * 256 + t) * 8;
    float4 a = *(const float4*)(in + idx);
    float4 b2 = *(const float4*)(in + idx + 4);
    u16x8 o;
    o[0] = f2bf(a.x); o[1] = f2bf(a.y); o[2] = f2bf(a.z); o[3] = f2bf(a.w);
    o[4] = f2bf(b2.x); o[5] = f2bf(b2.y); o[6] = f2bf(b2.z); o[7] = f2bf(b2.w);
    *(u16x8*)(outp + idx) = o;
    return;
  }
  const float* in; ushort* outp; int C, tb;
  if (b < 2176)      { in = qk_w; outp = wqkT; C = 1024; tb = b - 2048; }
  else if (b < 2240) { in = v_w;  outp = wvT;  C = 512;  tb = b - 2176; }
  else               { in = o_w;  outp = woT;  C = 512;  tb = b - 2240; }
  const int ctiles = C >> 6;
  const int ct = (tb % ctiles) * 64, rt = (tb / ctiles) * 64;
  const int lr = t >> 4, lc4 = (t & 15) * 4;
#pragma unroll
  for (int rep = 0; rep < 4; ++rep) {
    const int r = lr + rep * 16;
    float4 v = *(const float4*)(in + (size_t)(rt + r) * C + ct + lc4);
    Ts[r][lc4] = v.x; Ts[r][lc4 + 1] = v.y; Ts[r][lc4 + 2] = v.z; Ts[r][lc4 + 3] = v.w;
  }
  __syncthreads();
#pragma unroll
  for (int rep = 0; rep < 4; ++rep) {
    const int c = lr + rep * 16;
    u16x4 o;
    o[0] = f2bf(Ts[lc4 + 0][c]); o[1] = f2bf(Ts[lc4 + 1][c]);
    o[2] = f2bf(Ts[lc4 + 2][c]); o[3] = f2bf(Ts[lc4 + 3][c]);
    *(u16x4*)(outp + (size_t)(ct + c) * 512 + rt + lc4) = o;
  }
}

// ---------- projection GEMM, bf16 MFMA 16x16x32 (validated) ----------
// MODE 0: QK proj -> bf16 head-major [h][N][64] (q half pre-scaled by QK_LOG2E)
// MODE 1: V  proj -> bf16 transposed [h][64][N]
// MODE 2: out proj -> f32 [N][512] + bias
template<int MODE>
__global__ __launch_bounds__(256) void proj(
    const ushort* __restrict__ Wt, const ushort* __restrict__ Act,
    const float* __restrict__ bias, void* __restrict__ outp)
{
  __shared__ ushort hss[64 * 64];
  __shared__ ushort wts[64 * 64];
  const int mt64 = blockIdx.x, nt64 = blockIdx.y;
  const int t = threadIdx.x, w = t >> 6, lane = t & 63;
  const int r = lane, fr = lane & 15, fp = lane >> 4;

  const ushort* aRow = Act + (size_t)(mt64 * 64 + r) * 512;
  const ushort* wRow = Wt  + (size_t)(nt64 * 64 + r) * 512;

  u16x8 ha[2], wa[2];
#pragma unroll
  for (int rep = 0; rep < 2; ++rep) {
    ha[rep] = *(const u16x8*)(aRow + (w + rep * 4) * 8);
    wa[rep] = *(const u16x8*)(wRow + (w + rep * 4) * 8);
  }

  f32x4 acc[4] = {{0.f,0.f,0.f,0.f},{0.f,0.f,0.f,0.f},{0.f,0.f,0.f,0.f},{0.f,0.f,0.f,0.f}};

  for (int k0 = 0; k0 < 512; k0 += 64) {
    __syncthreads();
#pragma unroll
    for (int rep = 0; rep < 2; ++rep) {
      *(u16x8*)&hss[swz(r, (w + rep * 4) * 8)] = ha[rep];
      *(u16x8*)&wts[swz(r, (w + rep * 4) * 8)] = wa[rep];
    }
    __syncthreads();
    if (k0 + 64 < 512) {
#pragma unroll
      for (int rep = 0; rep < 2; ++rep) {
        ha[rep] = *(const u16x8*)(aRow + k0 + 64 + (w + rep * 4) * 8);
        wa[rep] = *(const u16x8*)(wRow + k0 + 64 + (w + rep * 4) * 8);
      }
    }
    const ushort* invT = (MODE == 1) ? hss : wts;
    const ushort* varT = (MODE == 1) ? wts : hss;
#pragma unroll
    for (int kh = 0; kh < 2; ++kh) {
      bf16x8 ia = *(const bf16x8*)&invT[swz(w * 16 + fr, fp * 8 + kh * 32)];
#pragma unroll
      for (int i = 0; i < 4; ++i) {
        bf16x8 vb = *(const bf16x8*)&varT[swz(i * 16 + fr, fp * 8 + kh * 32)];
        acc[i] = __builtin_amdgcn_mfma_f32_16x16x32_bf16(ia, vb, acc[i], 0, 0, 0);
      }
    }
  }

  if (MODE == 0) {
    ushort* out = (ushort*)outp;
    const int dq = w * 16 + fp * 4;
    const float scale = (nt64 < 8) ? QK_LOG2E : 1.0f;   // q half carries softmax scale
    float b4[4];
#pragma unroll
    for (int g = 0; g < 4; ++g) b4[g] = bias[nt64 * 64 + dq + g];
#pragma unroll
    for (int i = 0; i < 4; ++i) {
      const int m = mt64 * 64 + i * 16 + fr;
      u16x4 o;
#pragma unroll
      for (int g = 0; g < 4; ++g) o[g] = f2bf((acc[i][g] + b4[g]) * scale);
      *(u16x4*)(out + (size_t)nt64 * N_ELEC * DK + (size_t)m * DK + dq) = o;
    }
  } else if (MODE == 1) {
    ushort* out = (ushort*)outp;
    const int m0 = mt64 * 64 + w * 16 + fp * 4;
#pragma unroll
    for (int i = 0; i < 4; ++i) {
      const int n = nt64 * 64 + i * 16 + fr;
      const float bb = bias[n];
      u16x4 o;
#pragma unroll
      for (int g = 0; g < 4; ++g) o[g] = f2bf(acc[i][g] + bb);
      *(u16x4*)(out + (size_t)nt64 * DK * N_ELEC + (size_t)(i * 16 + fr) * N_ELEC + m0) = o;
    }
  } else {
    float* out = (float*)outp;
    const int n0 = nt64 * 64 + w * 16 + fp * 4;
    float4 bb = *(const float4*)(bias + n0);
#pragma unroll
    for (int i = 0; i < 4; ++i) {
      const int m = mt64 * 64 + i * 16 + fr;
      float4 o;
      o.x = acc[i][0] + bb.x; o.y = acc[i][1] + bb.y;
      o.z = acc[i][2] + bb.z; o.w = acc[i][3] + bb.w;
      *(float4*)(out + (size_t)m * DMODEL + n0) = o;
    }
  }
}

// ---------- flash attention (round-5 compute; gll double-buffered staging) ----------
// qb/kb: [h][4096][64] bf16 (q pre-scaled to exp2 domain), vtb: [h][64][4096] bf16.
// SPLIT==1: normalized bf16 vals [4096][512]. SPLIT==2: f32 partials + (m,l).
template<int SPLIT>
__global__ __launch_bounds__(256) void attn(
    const ushort* __restrict__ qb, const ushort* __restrict__ kb,
    const ushort* __restrict__ vtb, ushort* __restrict__ vals,
    float* __restrict__ Opart, float2* __restrict__ ML)
{
  __shared__ ushort Ks[2][64 * 64], Vts[2][64 * 64];
  __shared__ ushort Ps[4][16 * 64];
  const int bid = blockIdx.x;
  const int h = bid & 7, qt = (bid >> 3) & 63, s = bid >> 9;
  const int t = threadIdx.x, w = t >> 6, lane = t & 63;
  const int fr = lane & 15, fp = lane >> 4;
  const int KCH = N_ELEC / SPLIT, NT = KCH / 64;

  const ushort* kp = kb  + (size_t)h * N_ELEC * DK + (size_t)s * KCH * DK;
  const ushort* vp = vtb + (size_t)h * DK * N_ELEC + (size_t)s * KCH;
  const int q = qt * 64 + w * 16 + fr;

  // Q fragments direct from global
  bf16x8 qf0, qf1;
  {
    const ushort* qrow = qb + (size_t)h * N_ELEC * DK + (size_t)q * DK + fp * 8;
    qf0 = *(const bf16x8*)(qrow);
    qf1 = *(const bf16x8*)(qrow + 32);
  }

  // global_load_lds staging (rule #21): linear LDS dest, pre-swizzled global src.
  // Lane l of wave w writes LDS seg (w*2+p), row srow=l>>3, 16B chunk (l&7);
  // source chunk = (l&7) ^ (row&7) = (l&7) ^ (l>>3)  ->  LDS[r][x] = G[r][x^(r&7)],
  // which is exactly the swz() addressing the read side already uses.
  const int srow = lane >> 3;
  const int schunk = ((lane & 7) ^ srow) * 8;   // element offset of the 16B chunk

#define STAGE(buf, j0) do { \
  _Pragma("unroll") \
  for (int p = 0; p < 2; ++p) { \
    const int rr = (w * 2 + p) * 8 + srow; \
    GLL16(kp + (size_t)((j0) + rr) * DK + schunk, &Ks[buf][(w * 2 + p) * 512]); \
    GLL16(vp + (size_t)rr * N_ELEC + (j0) + schunk, &Vts[buf][(w * 2 + p) * 512]); \
  } \
} while (0)

  float mrun = -INFINITY, lsum = 0.f;
  f32x4 oacc[4] = {{0.f,0.f,0.f,0.f},{0.f,0.f,0.f,0.f},{0.f,0.f,0.f,0.f},{0.f,0.f,0.f,0.f}};

  STAGE(0, 0);
  asm volatile("s_waitcnt vmcnt(0)" ::: "memory");
  __syncthreads();

  for (int it = 0; it < NT; ++it) {
    const int cur = it & 1;
    if (it + 1 < NT) STAGE(cur ^ 1, (it + 1) * 64);   // other buffer is free past the barrier

    // S^T = K @ Q^T  (lane: k-rows = kt*16 + fp*4 + g, q-col = w*16 + fr)
    f32x4 sacc[4] = {{0.f,0.f,0.f,0.f},{0.f,0.f,0.f,0.f},{0.f,0.f,0.f,0.f},{0.f,0.f,0.f,0.f}};
#pragma unroll
    for (int kt = 0; kt < 4; ++kt) {
      bf16x8 a0 = *(const bf16x8*)&Ks[cur][swz(kt * 16 + fr, fp * 8)];
      bf16x8 a1 = *(const bf16x8*)&Ks[cur][swz(kt * 16 + fr, fp * 8 + 32)];
      sacc[kt] = __builtin_amdgcn_mfma_f32_16x16x32_bf16(a0, qf0, sacc[kt], 0, 0, 0);
      sacc[kt] = __builtin_amdgcn_mfma_f32_16x16x32_bf16(a1, qf1, sacc[kt], 0, 0, 0);
    }
    // online softmax in exp2 domain (scale already folded into q)
    float pv[16];
    float pm = -INFINITY;
#pragma unroll
    for (int kt = 0; kt < 4; ++kt)
#pragma unroll
      for (int g = 0; g < 4; ++g) {
        const float x = sacc[kt][g];
        pv[kt * 4 + g] = x;
        pm = fmaxf(pm, x);
      }
    pm = fmaxf(pm, __shfl_xor(pm, 16));
    pm = fmaxf(pm, __shfl_xor(pm, 32));
    if (__any(pm > mrun)) {                 // exact skip: corr==1 otherwise
      const float mnew = fmaxf(mrun, pm);
      const float corr = __builtin_amdgcn_exp2f(mrun - mnew);
      lsum *= corr;
#pragma unroll
      for (int dt = 0; dt < 4; ++dt) {
        oacc[dt][0] *= corr; oacc[dt][1] *= corr; oacc[dt][2] *= corr; oacc[dt][3] *= corr;
      }
      mrun = mnew;
    }
    float rs = 0.f;
#pragma unroll
    for (int i = 0; i < 16; ++i) { pv[i] = __builtin_amdgcn_exp2f(pv[i] - mrun); rs += pv[i]; }
    rs += __shfl_xor(rs, 16);
    rs += __shfl_xor(rs, 32);
    lsum += rs;
    // P -> per-wave LDS (row-major [16 q][64 k], swizzled), packed via cvt_pk
#pragma unroll
    for (int kt = 0; kt < 4; ++kt) {
      u32x2 pw;
      pw[0] = cvtpk(pv[kt * 4 + 0], pv[kt * 4 + 1]);
      pw[1] = cvtpk(pv[kt * 4 + 2], pv[kt * 4 + 3]);
      *(u32x2*)&Ps[w][swz(fr, kt * 16 + fp * 4)] = pw;
    }
    asm volatile("s_waitcnt lgkmcnt(0)" ::: "memory");  // intra-wave cross-lane P RAW
    // O^T += V^T @ P^T
    bf16x8 pf0 = *(const bf16x8*)&Ps[w][swz(fr, fp * 8)];
    bf16x8 pf1 = *(const bf16x8*)&Ps[w][swz(fr, fp * 8 + 32)];
#pragma unroll
    for (int dt = 0; dt < 4; ++dt) {
      bf16x8 v0 = *(const bf16x8*)&Vts[cur][swz(dt * 16 + fr, fp * 8)];
      bf16x8 v1 = *(const bf16x8*)&Vts[cur][swz(dt * 16 + fr, fp * 8 + 32)];
      oacc[dt] = __builtin_amdgcn_mfma_f32_16x16x32_bf16(v0, pf0, oacc[dt], 0, 0, 0);
      oacc[dt] = __builtin_amdgcn_mfma_f32_16x16x32_bf16(v1, pf1, oacc[dt], 0, 0, 0);
    }
    asm volatile("s_waitcnt vmcnt(0)" ::: "memory");   // next tile landed
    __syncthreads();
  }
#undef STAGE

  // epilogue: lane holds O^T[d = dt*16 + fp*4 + g][q = qt*64 + w*16 + fr]
  if constexpr (SPLIT == 1) {
    const float inv = 1.f / lsum;
#pragma unroll
    for (int dt = 0; dt < 4; ++dt) {
      u16x4 o;
#pragma unroll
      for (int g = 0; g < 4; ++g) o[g] = f2bf(oacc[dt][g] * inv);
      *(u16x4*)(vals + (size_t)q * DMODEL + h * DK + dt * 16 + fp * 4) = o;
    }
  } else {
    float* ob = Opart + ((size_t)(s * NHEADS + h) * N_ELEC + q) * DK;
#pragma unroll
    for (int dt = 0; dt < 4; ++dt) {
      float4 o;
      o.x = oacc[dt][0]; o.y = oacc[dt][1]; o.z = oacc[dt][2]; o.w = oacc[dt][3];
      *(float4*)(ob + dt * 16 + fp * 4) = o;
    }
    if (fp == 0) ML[(size_t)(s * NHEADS + h) * N_ELEC + q] = make_float2(mrun, lsum);
  }
}

// ---------- combine the 2 KV-splits ----------
__global__ __launch_bounds__(256) void combine(
    const float* __restrict__ Opart, const float2* __restrict__ ML,
    ushort* __restrict__ vals)
{
  const int rid = blockIdx.x * 4 + (threadIdx.x >> 6);  // h*4096 + q
  const int d = threadIdx.x & 63;
  const int hh = rid >> 12, qq = rid & 4095;
  const size_t base = (size_t)rid * DK + d;
  const size_t sstride = (size_t)NHEADS * N_ELEC * DK;
  float2 ml0 = ML[rid], ml1 = ML[(size_t)NHEADS * N_ELEC + rid];
  float o0 = Opart[base], o1 = Opart[sstride + base];
  float m = fmaxf(ml0.x, ml1.x);
  float c0 = __builtin_amdgcn_exp2f(ml0.x - m);
  float c1 = __builtin_amdgcn_exp2f(ml1.x - m);
  float l = c0 * ml0.y + c1 * ml1.y;
  vals[(size_t)qq * DMODEL + hh * DK + d] = f2bf((c0 * o0 + c1 * o1) / l);
}

extern "C" void kernel_launch(void* const* d_in, const int* in_sizes, int n_in,
                              void* d_out, int out_size, void* d_ws, size_t ws_size,
                              hipStream_t stream) {
  const float* hs   = (const float*)d_in[0];
  const float* hd   = (const float*)d_in[1];
  const float* qk_w = (const float*)d_in[2];
  const float* qk_b = (const float*)d_in[3];
  const float* v_w  = (const float*)d_in[4];
  const float* v_b  = (const float*)d_in[5];
  const float* o_w  = (const float*)d_in[6];
  const float* o_b  = (const float*)d_in[7];
  float* out = (float*)d_out;

  ushort* ws    = (ushort*)d_ws;
  ushort* hsb   = ws;                                   // [4096][512]
  ushort* hdb   = hsb  + (size_t)N_ELEC * DMODEL;
  ushort* wqkT  = hdb  + (size_t)N_ELEC * DMODEL;       // [1024][512]
  ushort* wvT   = wqkT + (size_t)1024 * 512;            // [512][512]
  ushort* woT   = wvT  + (size_t)512 * 512;             // [512][512]
  ushort* qbuf  = woT  + (size_t)512 * 512;             // [8][4096][64]
  ushort* kbuf  = qbuf + (size_t)NHEADS * N_ELEC * DK;  // [8][4096][64]
  ushort* vbufT = kbuf + (size_t)NHEADS * N_ELEC * DK;  // [8][64][4096]
  ushort* valsb = vbufT + (size_t)NHEADS * DK * N_ELEC; // [4096][512]
  float*  Opart = (float*)(valsb + (size_t)N_ELEC * DMODEL);   // [2][8][4096][64] f32
  float2* ML    = (float2*)(Opart + (size_t)2 * NHEADS * N_ELEC * DK);
  const size_t need = (size_t)((char*)(ML + (size_t)2 * NHEADS * N_ELEC) - (char*)d_ws);
  const bool split2 = ws_size >= need;

  dim3 blk(256);
  prep<<<dim3(2304), blk, 0, stream>>>(hs, hd, qk_w, v_w, o_w, hsb, hdb, wqkT, wvT, woT);
  proj<0><<<dim3(64, 16), blk, 0, stream>>>(wqkT, hsb, qk_b, qbuf);   // q (scaled) + k
  proj<1><<<dim3(64, 8),  blk, 0, stream>>>(wvT,  hdb, v_b,  vbufT);

  if (split2) {
    attn<2><<<dim3(1024), blk, 0, stream>>>(qbuf, kbuf, vbufT, nullptr, Opart, ML);
    combine<<<dim3(NHEADS * N_ELEC / 4), blk, 0, stream>>>(Opart, ML, valsb);
  } else {
    attn<1><<<dim3(512), blk, 0, stream>>>(qbuf, kbuf, vbufT, valsb, nullptr, nullptr);
  }

  proj<2><<<dim3(64, 8), blk, 0, stream>>>(woT, valsb, o_b, out);
}

// Round 7
// 117.172 us; speedup vs baseline: 7.8244x; 1.0672x over previous
//
#include <hip/hip_runtime.h>
#include <math.h>

#define N_ELEC 4096
#define DMODEL 512
#define NHEADS 8
#define DK 64

typedef __attribute__((ext_vector_type(8))) short  bf16x8;
typedef __attribute__((ext_vector_type(4))) float  f32x4;
typedef __attribute__((ext_vector_type(8))) ushort u16x8;
typedef __attribute__((ext_vector_type(4))) ushort u16x4;
typedef __attribute__((ext_vector_type(2))) unsigned int u32x2;

// XOR-swizzle for [R][64] bf16 tiles (row stride 128B)
__device__ __forceinline__ int swz(int r, int c) { return r * 64 + (c ^ ((r & 7) * 8)); }

__device__ __forceinline__ ushort f2bf(float f) {
  union { float f; unsigned int u; } cv; cv.f = f;
  unsigned int u = cv.u;
  u += 0x7FFFu + ((u >> 16) & 1u);   // RNE
  return (ushort)(u >> 16);
}

__device__ __forceinline__ unsigned cvtpk(float lo, float hi) {
  unsigned r;
  asm("v_cvt_pk_bf16_f32 %0, %1, %2" : "=v"(r) : "v"(lo), "v"(hi));
  return r;
}

#define GLL16(gp, lp) __builtin_amdgcn_global_load_lds( \
    (const __attribute__((address_space(1))) void*)(gp), \
    (__attribute__((address_space(3))) void*)(lp), 16, 0, 0)

#define QK_LOG2E 0.18033688f   // 0.125 * log2(e), folded into q at projection time

// ---------- fused prep: f32->bf16 conv of hs/hd + 3 weight transposes ----------
__global__ __launch_bounds__(256) void prep(
    const float* __restrict__ hs, const float* __restrict__ hd,
    const float* __restrict__ qk_w, const float* __restrict__ v_w, const float* __restrict__ o_w,
    ushort* __restrict__ hsb, ushort* __restrict__ hdb,
    ushort* __restrict__ wqkT, ushort* __restrict__ wvT, ushort* __restrict__ woT)
{
  __shared__ float Ts[64][68];
  const int b = blockIdx.x, t = threadIdx.x;
  if (b < 2048) {
    const float* in = (b < 1024) ? hs : hd;
    ushort* outp = (b < 1024) ? hsb : hdb;
    const int idx = ((b & 1023) * 256 + t) * 8;
    float4 a = *(const float4*)(in + idx);
    float4 b2 = *(const float4*)(in + idx + 4);
    u16x8 o;
    o[0] = f2bf(a.x); o[1] = f2bf(a.y); o[2] = f2bf(a.z); o[3] = f2bf(a.w);
    o[4] = f2bf(b2.x); o[5] = f2bf(b2.y); o[6] = f2bf(b2.z); o[7] = f2bf(b2.w);
    *(u16x8*)(outp + idx) = o;
    return;
  }
  const float* in; ushort* outp; int C, tb;
  if (b < 2176)      { in = qk_w; outp = wqkT; C = 1024; tb = b - 2048; }
  else if (b < 2240) { in = v_w;  outp = wvT;  C = 512;  tb = b - 2176; }
  else               { in = o_w;  outp = woT;  C = 512;  tb = b - 2240; }
  const int ctiles = C >> 6;
  const int ct = (tb % ctiles) * 64, rt = (tb / ctiles) * 64;
  const int lr = t >> 4, lc4 = (t & 15) * 4;
#pragma unroll
  for (int rep = 0; rep < 4; ++rep) {
    const int r = lr + rep * 16;
    float4 v = *(const float4*)(in + (size_t)(rt + r) * C + ct + lc4);
    Ts[r][lc4] = v.x; Ts[r][lc4 + 1] = v.y; Ts[r][lc4 + 2] = v.z; Ts[r][lc4 + 3] = v.w;
  }
  __syncthreads();
#pragma unroll
  for (int rep = 0; rep < 4; ++rep) {
    const int c = lr + rep * 16;
    u16x4 o;
    o[0] = f2bf(Ts[lc4 + 0][c]); o[1] = f2bf(Ts[lc4 + 1][c]);
    o[2] = f2bf(Ts[lc4 + 2][c]); o[3] = f2bf(Ts[lc4 + 3][c]);
    *(u16x4*)(outp + (size_t)(ct + c) * 512 + rt + lc4) = o;
  }
}

// ---------- projection GEMM, 128x128 tile, gll-staged dbuf ----------
// A-operand rows ("R"), B-operand rows ("C"); D[R][C]; both tiles [128][64k].
// MODE 0: R=wqkT(n), C=hsb(m) -> bf16 head-major q|k [h][N][64], q half scaled
// MODE 1: R=hdb(m),  C=wvT(n) -> bf16 transposed V [h][64][N]
// MODE 2: R=woT(n),  C=vals(m)-> f32 out [N][512] + bias
template<int MODE>
__global__ __launch_bounds__(256) void proj128(
    const ushort* __restrict__ Wt, const ushort* __restrict__ Act,
    const float* __restrict__ bias, void* __restrict__ outp)
{
  __shared__ ushort At[2][128 * 64];
  __shared__ ushort Bt[2][128 * 64];
  const int mt = blockIdx.x, nt = blockIdx.y;
  const int t = threadIdx.x, w = t >> 6, lane = t & 63;
  const int fr = lane & 15, fp = lane >> 4;

  const ushort* rowsA = (MODE == 1) ? Act + (size_t)mt * 128 * 512 : Wt + (size_t)nt * 128 * 512;
  const ushort* rowsB = (MODE == 1) ? Wt + (size_t)nt * 128 * 512 : Act + (size_t)mt * 128 * 512;

  // staging: 1024 chunks (16B) per tile; thread t does 4; dest linear, src pre-swizzled
#define STAGEP(buf, k0) do { \
  _Pragma("unroll") \
  for (int rep = 0; rep < 4; ++rep) { \
    const int cid = rep * 256 + t; \
    const int row_ = cid >> 3; \
    const int sc = ((cid & 7) ^ (row_ & 7)) * 8; \
    GLL16(rowsA + (size_t)row_ * 512 + (k0) + sc, &At[buf][(rep * 256 + w * 64) * 8]); \
    GLL16(rowsB + (size_t)row_ * 512 + (k0) + sc, &Bt[buf][(rep * 256 + w * 64) * 8]); \
  } \
} while (0)

  const int rbase = (w >> 1) * 64;   // wave's A-row half
  const int cbase = (w & 1) * 64;    // wave's B-row half

  f32x4 acc[16];
#pragma unroll
  for (int i = 0; i < 16; ++i) acc[i] = (f32x4){0.f, 0.f, 0.f, 0.f};

  STAGEP(0, 0);
  asm volatile("s_waitcnt vmcnt(0)" ::: "memory");
  __syncthreads();

  for (int it = 0; it < 8; ++it) {
    const int cur = it & 1;
    if (it < 7) STAGEP(cur ^ 1, (it + 1) * 64);
#pragma unroll
    for (int kh = 0; kh < 2; ++kh) {
      bf16x8 af[4], bf[4];
#pragma unroll
      for (int i = 0; i < 4; ++i) {
        af[i] = *(const bf16x8*)&At[cur][swz(rbase + i * 16 + fr, kh * 32 + fp * 8)];
        bf[i] = *(const bf16x8*)&Bt[cur][swz(cbase + i * 16 + fr, kh * 32 + fp * 8)];
      }
#pragma unroll
      for (int i = 0; i < 4; ++i)
#pragma unroll
        for (int j = 0; j < 4; ++j)
          acc[i * 4 + j] = __builtin_amdgcn_mfma_f32_16x16x32_bf16(af[i], bf[j], acc[i * 4 + j], 0, 0, 0);
    }
    asm volatile("s_waitcnt vmcnt(0)" ::: "memory");
    __syncthreads();
  }
#undef STAGEP

  // epilogue: acc[i*4+j] frag: Drow = rbase_g + i*16 + fp*4 + g, Dcol = cbase_g + j*16 + fr
  if (MODE == 0) {
    ushort* out = (ushort*)outp;
#pragma unroll
    for (int i = 0; i < 4; ++i) {
      const int nb = nt * 128 + rbase + i * 16 + fp * 4;   // qk-col (0..1023)
      const float scale = (nb < 512) ? QK_LOG2E : 1.0f;
      const float4 bb = *(const float4*)(bias + nb);
      const int h = nb >> 6, d0 = nb & 63;
#pragma unroll
      for (int j = 0; j < 4; ++j) {
        const int m = mt * 128 + cbase + j * 16 + fr;
        const f32x4 a = acc[i * 4 + j];
        u16x4 o;
        o[0] = f2bf((a[0] + bb.x) * scale); o[1] = f2bf((a[1] + bb.y) * scale);
        o[2] = f2bf((a[2] + bb.z) * scale); o[3] = f2bf((a[3] + bb.w) * scale);
        *(u16x4*)(out + (size_t)h * N_ELEC * DK + (size_t)m * DK + d0) = o;
      }
    }
  } else if (MODE == 1) {
    ushort* out = (ushort*)outp;
#pragma unroll
    for (int j = 0; j < 4; ++j) {
      const int n = nt * 128 + cbase + j * 16 + fr;        // model-dim d (0..511)
      const float bb = bias[n];
      const int h = n >> 6, dd = n & 63;
#pragma unroll
      for (int i = 0; i < 4; ++i) {
        const int m0 = mt * 128 + rbase + i * 16 + fp * 4;
        const f32x4 a = acc[i * 4 + j];
        u16x4 o;
        o[0] = f2bf(a[0] + bb); o[1] = f2bf(a[1] + bb);
        o[2] = f2bf(a[2] + bb); o[3] = f2bf(a[3] + bb);
        *(u16x4*)(out + (size_t)h * DK * N_ELEC + (size_t)dd * N_ELEC + m0) = o;
      }
    }
  } else {
    float* out = (float*)outp;
#pragma unroll
    for (int i = 0; i < 4; ++i) {
      const int n0 = nt * 128 + rbase + i * 16 + fp * 4;   // out col (0..511)
      const float4 bb = *(const float4*)(bias + n0);
#pragma unroll
      for (int j = 0; j < 4; ++j) {
        const int m = mt * 128 + cbase + j * 16 + fr;
        const f32x4 a = acc[i * 4 + j];
        float4 o;
        o.x = a[0] + bb.x; o.y = a[1] + bb.y; o.z = a[2] + bb.z; o.w = a[3] + bb.w;
        *(float4*)(out + (size_t)m * DMODEL + n0) = o;
      }
    }
  }
}

// ---------- flash attention (round-6 validated; unchanged) ----------
template<int SPLIT>
__global__ __launch_bounds__(256) void attn(
    const ushort* __restrict__ qb, const ushort* __restrict__ kb,
    const ushort* __restrict__ vtb, ushort* __restrict__ vals,
    float* __restrict__ Opart, float2* __restrict__ ML)
{
  __shared__ ushort Ks[2][64 * 64], Vts[2][64 * 64];
  __shared__ ushort Ps[4][16 * 64];
  const int bid = blockIdx.x;
  const int h = bid & 7, qt = (bid >> 3) & 63, s = bid >> 9;
  const int t = threadIdx.x, w = t >> 6, lane = t & 63;
  const int fr = lane & 15, fp = lane >> 4;
  const int KCH = N_ELEC / SPLIT;

  const ushort* kp = kb  + (size_t)h * N_ELEC * DK + (size_t)s * KCH * DK;
  const ushort* vp = vtb + (size_t)h * DK * N_ELEC + (size_t)s * KCH;
  const int q = qt * 64 + w * 16 + fr;

  bf16x8 qf0, qf1;
  {
    const ushort* qrow = qb + (size_t)h * N_ELEC * DK + (size_t)q * DK + fp * 8;
    qf0 = *(const bf16x8*)(qrow);
    qf1 = *(const bf16x8*)(qrow + 32);
  }

  const int srow = lane >> 3;
  const int schunk = ((lane & 7) ^ srow) * 8;

#define STAGE(buf, j0) do { \
  _Pragma("unroll") \
  for (int p = 0; p < 2; ++p) { \
    const int rr = (w * 2 + p) * 8 + srow; \
    GLL16(kp + (size_t)((j0) + rr) * DK + schunk, &Ks[buf][(w * 2 + p) * 512]); \
    GLL16(vp + (size_t)rr * N_ELEC + (j0) + schunk, &Vts[buf][(w * 2 + p) * 512]); \
  } \
} while (0)

  float mrun = -INFINITY, lsum = 0.f;
  f32x4 oacc[4] = {{0.f,0.f,0.f,0.f},{0.f,0.f,0.f,0.f},{0.f,0.f,0.f,0.f},{0.f,0.f,0.f,0.f}};

  STAGE(0, 0);
  asm volatile("s_waitcnt vmcnt(0)" ::: "memory");
  __syncthreads();

  for (int it = 0; it < KCH / 64; ++it) {
    const int cur = it & 1;
    if ((it + 1) * 64 < KCH) STAGE(cur ^ 1, (it + 1) * 64);

    f32x4 sacc[4] = {{0.f,0.f,0.f,0.f},{0.f,0.f,0.f,0.f},{0.f,0.f,0.f,0.f},{0.f,0.f,0.f,0.f}};
#pragma unroll
    for (int kt = 0; kt < 4; ++kt) {
      bf16x8 a0 = *(const bf16x8*)&Ks[cur][swz(kt * 16 + fr, fp * 8)];
      bf16x8 a1 = *(const bf16x8*)&Ks[cur][swz(kt * 16 + fr, fp * 8 + 32)];
      sacc[kt] = __builtin_amdgcn_mfma_f32_16x16x32_bf16(a0, qf0, sacc[kt], 0, 0, 0);
      sacc[kt] = __builtin_amdgcn_mfma_f32_16x16x32_bf16(a1, qf1, sacc[kt], 0, 0, 0);
    }
    float pv[16];
    float pm = -INFINITY;
#pragma unroll
    for (int kt = 0; kt < 4; ++kt)
#pragma unroll
      for (int g = 0; g < 4; ++g) {
        const float x = sacc[kt][g];
        pv[kt * 4 + g] = x;
        pm = fmaxf(pm, x);
      }
    pm = fmaxf(pm, __shfl_xor(pm, 16));
    pm = fmaxf(pm, __shfl_xor(pm, 32));
    if (__any(pm > mrun)) {
      const float mnew = fmaxf(mrun, pm);
      const float corr = __builtin_amdgcn_exp2f(mrun - mnew);
      lsum *= corr;
#pragma unroll
      for (int dt = 0; dt < 4; ++dt) {
        oacc[dt][0] *= corr; oacc[dt][1] *= corr; oacc[dt][2] *= corr; oacc[dt][3] *= corr;
      }
      mrun = mnew;
    }
    float rs = 0.f;
#pragma unroll
    for (int i = 0; i < 16; ++i) { pv[i] = __builtin_amdgcn_exp2f(pv[i] - mrun); rs += pv[i]; }
    rs += __shfl_xor(rs, 16);
    rs += __shfl_xor(rs, 32);
    lsum += rs;
#pragma unroll
    for (int kt = 0; kt < 4; ++kt) {
      u32x2 pw;
      pw[0] = cvtpk(pv[kt * 4 + 0], pv[kt * 4 + 1]);
      pw[1] = cvtpk(pv[kt * 4 + 2], pv[kt * 4 + 3]);
      *(u32x2*)&Ps[w][swz(fr, kt * 16 + fp * 4)] = pw;
    }
    asm volatile("s_waitcnt lgkmcnt(0)" ::: "memory");
    bf16x8 pf0 = *(const bf16x8*)&Ps[w][swz(fr, fp * 8)];
    bf16x8 pf1 = *(const bf16x8*)&Ps[w][swz(fr, fp * 8 + 32)];
#pragma unroll
    for (int dt = 0; dt < 4; ++dt) {
      bf16x8 v0 = *(const bf16x8*)&Vts[cur][swz(dt * 16 + fr, fp * 8)];
      bf16x8 v1 = *(const bf16x8*)&Vts[cur][swz(dt * 16 + fr, fp * 8 + 32)];
      oacc[dt] = __builtin_amdgcn_mfma_f32_16x16x32_bf16(v0, pf0, oacc[dt], 0, 0, 0);
      oacc[dt] = __builtin_amdgcn_mfma_f32_16x16x32_bf16(v1, pf1, oacc[dt], 0, 0, 0);
    }
    asm volatile("s_waitcnt vmcnt(0)" ::: "memory");
    __syncthreads();
  }
#undef STAGE

  if constexpr (SPLIT == 1) {
    const float inv = 1.f / lsum;
#pragma unroll
    for (int dt = 0; dt < 4; ++dt) {
      u16x4 o;
#pragma unroll
      for (int g = 0; g < 4; ++g) o[g] = f2bf(oacc[dt][g] * inv);
      *(u16x4*)(vals + (size_t)q * DMODEL + h * DK + dt * 16 + fp * 4) = o;
    }
  } else {
    float* ob = Opart + ((size_t)(s * NHEADS + h) * N_ELEC + q) * DK;
#pragma unroll
    for (int dt = 0; dt < 4; ++dt) {
      float4 o;
      o.x = oacc[dt][0]; o.y = oacc[dt][1]; o.z = oacc[dt][2]; o.w = oacc[dt][3];
      *(float4*)(ob + dt * 16 + fp * 4) = o;
    }
    if (fp == 0) ML[(size_t)(s * NHEADS + h) * N_ELEC + q] = make_float2(mrun, lsum);
  }
}

// ---------- combine the 2 KV-splits ----------
__global__ __launch_bounds__(256) void combine(
    const float* __restrict__ Opart, const float2* __restrict__ ML,
    ushort* __restrict__ vals)
{
  const int rid = blockIdx.x * 4 + (threadIdx.x >> 6);  // h*4096 + q
  const int d = threadIdx.x & 63;
  const int hh = rid >> 12, qq = rid & 4095;
  const size_t base = (size_t)rid * DK + d;
  const size_t sstride = (size_t)NHEADS * N_ELEC * DK;
  float2 ml0 = ML[rid], ml1 = ML[(size_t)NHEADS * N_ELEC + rid];
  float o0 = Opart[base], o1 = Opart[sstride + base];
  float m = fmaxf(ml0.x, ml1.x);
  float c0 = __builtin_amdgcn_exp2f(ml0.x - m);
  float c1 = __builtin_amdgcn_exp2f(ml1.x - m);
  float l = c0 * ml0.y + c1 * ml1.y;
  vals[(size_t)qq * DMODEL + hh * DK + d] = f2bf((c0 * o0 + c1 * o1) / l);
}

extern "C" void kernel_launch(void* const* d_in, const int* in_sizes, int n_in,
                              void* d_out, int out_size, void* d_ws, size_t ws_size,
                              hipStream_t stream) {
  const float* hs   = (const float*)d_in[0];
  const float* hd   = (const float*)d_in[1];
  const float* qk_w = (const float*)d_in[2];
  const float* qk_b = (const float*)d_in[3];
  const float* v_w  = (const float*)d_in[4];
  const float* v_b  = (const float*)d_in[5];
  const float* o_w  = (const float*)d_in[6];
  const float* o_b  = (const float*)d_in[7];
  float* out = (float*)d_out;

  ushort* ws    = (ushort*)d_ws;
  ushort* hsb   = ws;                                   // [4096][512]
  ushort* hdb   = hsb  + (size_t)N_ELEC * DMODEL;
  ushort* wqkT  = hdb  + (size_t)N_ELEC * DMODEL;       // [1024][512]
  ushort* wvT   = wqkT + (size_t)1024 * 512;            // [512][512]
  ushort* woT   = wvT  + (size_t)512 * 512;             // [512][512]
  ushort* qbuf  = woT  + (size_t)512 * 512;             // [8][4096][64]
  ushort* kbuf  = qbuf + (size_t)NHEADS * N_ELEC * DK;  // [8][4096][64]
  ushort* vbufT = kbuf + (size_t)NHEADS * N_ELEC * DK;  // [8][64][4096]
  ushort* valsb = vbufT + (size_t)NHEADS * DK * N_ELEC; // [4096][512]
  float*  Opart = (float*)(valsb + (size_t)N_ELEC * DMODEL);   // [2][8][4096][64] f32
  float2* ML    = (float2*)(Opart + (size_t)2 * NHEADS * N_ELEC * DK);
  const size_t need = (size_t)((char*)(ML + (size_t)2 * NHEADS * N_ELEC) - (char*)d_ws);
  const bool split2 = ws_size >= need;

  dim3 blk(256);
  prep<<<dim3(2304), blk, 0, stream>>>(hs, hd, qk_w, v_w, o_w, hsb, hdb, wqkT, wvT, woT);
  proj128<0><<<dim3(32, 8), blk, 0, stream>>>(wqkT, hsb, qk_b, qbuf);   // q (scaled) + k
  proj128<1><<<dim3(32, 4), blk, 0, stream>>>(wvT,  hdb, v_b,  vbufT);

  if (split2) {
    attn<2><<<dim3(1024), blk, 0, stream>>>(qbuf, kbuf, vbufT, nullptr, Opart, ML);
    combine<<<dim3(NHEADS * N_ELEC / 4), blk, 0, stream>>>(Opart, ML, valsb);
  } else {
    attn<1><<<dim3(512), blk, 0, stream>>>(qbuf, kbuf, vbufT, valsb, nullptr, nullptr);
  }

  proj128<2><<<dim3(32, 4), blk, 0, stream>>>(woT, valsb, o_b, out);
}

// Round 8
// 116.697 us; speedup vs baseline: 7.8563x; 1.0041x over previous
//
#include <hip/hip_runtime.h>
#include <math.h>

#define N_ELEC 4096
#define DMODEL 512
#define NHEADS 8
#define DK 64

typedef __attribute__((ext_vector_type(8))) short  bf16x8;
typedef __attribute__((ext_vector_type(4))) float  f32x4;
typedef __attribute__((ext_vector_type(8))) ushort u16x8;
typedef __attribute__((ext_vector_type(4))) ushort u16x4;
typedef __attribute__((ext_vector_type(2))) unsigned int u32x2;

// XOR-swizzle for [R][64] bf16 tiles (row stride 128B)
__device__ __forceinline__ int swz(int r, int c) { return r * 64 + (c ^ ((r & 7) * 8)); }

__device__ __forceinline__ ushort f2bf(float f) {
  union { float f; unsigned int u; } cv; cv.f = f;
  unsigned int u = cv.u;
  u += 0x7FFFu + ((u >> 16) & 1u);   // RNE
  return (ushort)(u >> 16);
}

__device__ __forceinline__ unsigned cvtpk(float lo, float hi) {
  unsigned r;
  asm("v_cvt_pk_bf16_f32 %0, %1, %2" : "=v"(r) : "v"(lo), "v"(hi));
  return r;
}

#define GLL16(gp, lp) __builtin_amdgcn_global_load_lds( \
    (const __attribute__((address_space(1))) void*)(gp), \
    (__attribute__((address_space(3))) void*)(lp), 16, 0, 0)

#define QK_LOG2E 0.18033688f   // 0.125 * log2(e), folded into q at projection time

// ---------- fused prep: f32->bf16 conv of hs/hd + 3 weight transposes ----------
__global__ __launch_bounds__(256) void prep(
    const float* __restrict__ hs, const float* __restrict__ hd,
    const float* __restrict__ qk_w, const float* __restrict__ v_w, const float* __restrict__ o_w,
    ushort* __restrict__ hsb, ushort* __restrict__ hdb,
    ushort* __restrict__ wqkT, ushort* __restrict__ wvT, ushort* __restrict__ woT)
{
  __shared__ float Ts[64][68];
  const int b = blockIdx.x, t = threadIdx.x;
  if (b < 2048) {
    const float* in = (b < 1024) ? hs : hd;
    ushort* outp = (b < 1024) ? hsb : hdb;
    const int idx = ((b & 1023) * 256 + t) * 8;
    float4 a = *(const float4*)(in + idx);
    float4 b2 = *(const float4*)(in + idx + 4);
    u16x8 o;
    o[0] = f2bf(a.x); o[1] = f2bf(a.y); o[2] = f2bf(a.z); o[3] = f2bf(a.w);
    o[4] = f2bf(b2.x); o[5] = f2bf(b2.y); o[6] = f2bf(b2.z); o[7] = f2bf(b2.w);
    *(u16x8*)(outp + idx) = o;
    return;
  }
  const float* in; ushort* outp; int C, tb;
  if (b < 2176)      { in = qk_w; outp = wqkT; C = 1024; tb = b - 2048; }
  else if (b < 2240) { in = v_w;  outp = wvT;  C = 512;  tb = b - 2176; }
  else               { in = o_w;  outp = woT;  C = 512;  tb = b - 2240; }
  const int ctiles = C >> 6;
  const int ct = (tb % ctiles) * 64, rt = (tb / ctiles) * 64;
  const int lr = t >> 4, lc4 = (t & 15) * 4;
#pragma unroll
  for (int rep = 0; rep < 4; ++rep) {
    const int r = lr + rep * 16;
    float4 v = *(const float4*)(in + (size_t)(rt + r) * C + ct + lc4);
    Ts[r][lc4] = v.x; Ts[r][lc4 + 1] = v.y; Ts[r][lc4 + 2] = v.z; Ts[r][lc4 + 3] = v.w;
  }
  __syncthreads();
#pragma unroll
  for (int rep = 0; rep < 4; ++rep) {
    const int c = lr + rep * 16;
    u16x4 o;
    o[0] = f2bf(Ts[lc4 + 0][c]); o[1] = f2bf(Ts[lc4 + 1][c]);
    o[2] = f2bf(Ts[lc4 + 2][c]); o[3] = f2bf(Ts[lc4 + 3][c]);
    *(u16x4*)(outp + (size_t)(ct + c) * 512 + rt + lc4) = o;
  }
}

// ---------- projection GEMM, 128x128 tile, gll-staged dbuf (round-7 validated) ----------
template<int MODE>
__global__ __launch_bounds__(256) void proj128(
    const ushort* __restrict__ Wt, const ushort* __restrict__ Act,
    const float* __restrict__ bias, void* __restrict__ outp)
{
  __shared__ ushort At[2][128 * 64];
  __shared__ ushort Bt[2][128 * 64];
  const int mt = blockIdx.x, nt = blockIdx.y;
  const int t = threadIdx.x, w = t >> 6, lane = t & 63;
  const int fr = lane & 15, fp = lane >> 4;

  const ushort* rowsA = (MODE == 1) ? Act + (size_t)mt * 128 * 512 : Wt + (size_t)nt * 128 * 512;
  const ushort* rowsB = (MODE == 1) ? Wt + (size_t)nt * 128 * 512 : Act + (size_t)mt * 128 * 512;

#define STAGEP(buf, k0) do { \
  _Pragma("unroll") \
  for (int rep = 0; rep < 4; ++rep) { \
    const int cid = rep * 256 + t; \
    const int row_ = cid >> 3; \
    const int sc = ((cid & 7) ^ (row_ & 7)) * 8; \
    GLL16(rowsA + (size_t)row_ * 512 + (k0) + sc, &At[buf][(rep * 256 + w * 64) * 8]); \
    GLL16(rowsB + (size_t)row_ * 512 + (k0) + sc, &Bt[buf][(rep * 256 + w * 64) * 8]); \
  } \
} while (0)

  const int rbase = (w >> 1) * 64;
  const int cbase = (w & 1) * 64;

  f32x4 acc[16];
#pragma unroll
  for (int i = 0; i < 16; ++i) acc[i] = (f32x4){0.f, 0.f, 0.f, 0.f};

  STAGEP(0, 0);
  asm volatile("s_waitcnt vmcnt(0)" ::: "memory");
  __syncthreads();

  for (int it = 0; it < 8; ++it) {
    const int cur = it & 1;
    if (it < 7) STAGEP(cur ^ 1, (it + 1) * 64);
#pragma unroll
    for (int kh = 0; kh < 2; ++kh) {
      bf16x8 af[4], bf[4];
#pragma unroll
      for (int i = 0; i < 4; ++i) {
        af[i] = *(const bf16x8*)&At[cur][swz(rbase + i * 16 + fr, kh * 32 + fp * 8)];
        bf[i] = *(const bf16x8*)&Bt[cur][swz(cbase + i * 16 + fr, kh * 32 + fp * 8)];
      }
#pragma unroll
      for (int i = 0; i < 4; ++i)
#pragma unroll
        for (int j = 0; j < 4; ++j)
          acc[i * 4 + j] = __builtin_amdgcn_mfma_f32_16x16x32_bf16(af[i], bf[j], acc[i * 4 + j], 0, 0, 0);
    }
    asm volatile("s_waitcnt vmcnt(0)" ::: "memory");
    __syncthreads();
  }
#undef STAGEP

  if (MODE == 0) {
    ushort* out = (ushort*)outp;
#pragma unroll
    for (int i = 0; i < 4; ++i) {
      const int nb = nt * 128 + rbase + i * 16 + fp * 4;
      const float scale = (nb < 512) ? QK_LOG2E : 1.0f;
      const float4 bb = *(const float4*)(bias + nb);
      const int h = nb >> 6, d0 = nb & 63;
#pragma unroll
      for (int j = 0; j < 4; ++j) {
        const int m = mt * 128 + cbase + j * 16 + fr;
        const f32x4 a = acc[i * 4 + j];
        u16x4 o;
        o[0] = f2bf((a[0] + bb.x) * scale); o[1] = f2bf((a[1] + bb.y) * scale);
        o[2] = f2bf((a[2] + bb.z) * scale); o[3] = f2bf((a[3] + bb.w) * scale);
        *(u16x4*)(out + (size_t)h * N_ELEC * DK + (size_t)m * DK + d0) = o;
      }
    }
  } else if (MODE == 1) {
    ushort* out = (ushort*)outp;
#pragma unroll
    for (int j = 0; j < 4; ++j) {
      const int n = nt * 128 + cbase + j * 16 + fr;
      const float bb = bias[n];
      const int h = n >> 6, dd = n & 63;
#pragma unroll
      for (int i = 0; i < 4; ++i) {
        const int m0 = mt * 128 + rbase + i * 16 + fp * 4;
        const f32x4 a = acc[i * 4 + j];
        u16x4 o;
        o[0] = f2bf(a[0] + bb); o[1] = f2bf(a[1] + bb);
        o[2] = f2bf(a[2] + bb); o[3] = f2bf(a[3] + bb);
        *(u16x4*)(out + (size_t)h * DK * N_ELEC + (size_t)dd * N_ELEC + m0) = o;
      }
    }
  } else {
    float* out = (float*)outp;
#pragma unroll
    for (int i = 0; i < 4; ++i) {
      const int n0 = nt * 128 + rbase + i * 16 + fp * 4;
      const float4 bb = *(const float4*)(bias + n0);
#pragma unroll
      for (int j = 0; j < 4; ++j) {
        const int m = mt * 128 + cbase + j * 16 + fr;
        const f32x4 a = acc[i * 4 + j];
        float4 o;
        o.x = a[0] + bb.x; o.y = a[1] + bb.y; o.z = a[2] + bb.z; o.w = a[3] + bb.w;
        *(float4*)(out + (size_t)m * DMODEL + n0) = o;
      }
    }
  }
}

// ---------- flash attention: QBLK=128 (32 q per wave, 2 q-subtiles) ----------
// K/V fragments (A-operands) read once per wave-iter, shared across both q-subtiles.
template<int SPLIT>
__global__ __launch_bounds__(256) void attn(
    const ushort* __restrict__ qb, const ushort* __restrict__ kb,
    const ushort* __restrict__ vtb, ushort* __restrict__ vals,
    float* __restrict__ Opart, float2* __restrict__ ML)
{
  __shared__ ushort Ks[2][64 * 64], Vts[2][64 * 64];
  __shared__ ushort Ps[4][2][16 * 64];
  const int bid = blockIdx.x;
  const int h = bid & 7, qt = (bid >> 3) & 31, s = bid >> 8;
  const int t = threadIdx.x, w = t >> 6, lane = t & 63;
  const int fr = lane & 15, fp = lane >> 4;
  const int KCH = N_ELEC / SPLIT;

  const ushort* kp = kb  + (size_t)h * N_ELEC * DK + (size_t)s * KCH * DK;
  const ushort* vp = vtb + (size_t)h * DK * N_ELEC + (size_t)s * KCH;
  const int q0 = qt * 128 + w * 32;   // wave's q base; subtile qs adds 16

  // Q fragments direct from global (per q-subtile)
  bf16x8 qf[2][2];
#pragma unroll
  for (int qs = 0; qs < 2; ++qs) {
    const ushort* qrow = qb + (size_t)h * N_ELEC * DK + (size_t)(q0 + qs * 16 + fr) * DK + fp * 8;
    qf[qs][0] = *(const bf16x8*)(qrow);
    qf[qs][1] = *(const bf16x8*)(qrow + 32);
  }

  const int srow = lane >> 3;
  const int schunk = ((lane & 7) ^ srow) * 8;

#define STAGE(buf, j0) do { \
  _Pragma("unroll") \
  for (int p = 0; p < 2; ++p) { \
    const int rr = (w * 2 + p) * 8 + srow; \
    GLL16(kp + (size_t)((j0) + rr) * DK + schunk, &Ks[buf][(w * 2 + p) * 512]); \
    GLL16(vp + (size_t)rr * N_ELEC + (j0) + schunk, &Vts[buf][(w * 2 + p) * 512]); \
  } \
} while (0)

  float mrun[2] = {-INFINITY, -INFINITY}, lsum[2] = {0.f, 0.f};
  f32x4 oacc[2][4];
#pragma unroll
  for (int qs = 0; qs < 2; ++qs)
#pragma unroll
    for (int dt = 0; dt < 4; ++dt) oacc[qs][dt] = (f32x4){0.f, 0.f, 0.f, 0.f};

  STAGE(0, 0);
  asm volatile("s_waitcnt vmcnt(0)" ::: "memory");
  __syncthreads();

  for (int it = 0; it < KCH / 64; ++it) {
    const int cur = it & 1;
    if ((it + 1) * 64 < KCH) STAGE(cur ^ 1, (it + 1) * 64);

    // K fragments: read ONCE, shared by both q-subtiles
    bf16x8 ka[4][2];
#pragma unroll
    for (int kt = 0; kt < 4; ++kt) {
      ka[kt][0] = *(const bf16x8*)&Ks[cur][swz(kt * 16 + fr, fp * 8)];
      ka[kt][1] = *(const bf16x8*)&Ks[cur][swz(kt * 16 + fr, fp * 8 + 32)];
    }
    // S^T = K @ Q^T per q-subtile
    f32x4 sacc[2][4];
#pragma unroll
    for (int qs = 0; qs < 2; ++qs)
#pragma unroll
      for (int kt = 0; kt < 4; ++kt) {
        f32x4 z = {0.f, 0.f, 0.f, 0.f};
        z = __builtin_amdgcn_mfma_f32_16x16x32_bf16(ka[kt][0], qf[qs][0], z, 0, 0, 0);
        sacc[qs][kt] = __builtin_amdgcn_mfma_f32_16x16x32_bf16(ka[kt][1], qf[qs][1], z, 0, 0, 0);
      }
    // online softmax per q-subtile (exp2 domain; exp2 in place, no pv copy)
#pragma unroll
    for (int qs = 0; qs < 2; ++qs) {
      float pm = -INFINITY;
#pragma unroll
      for (int kt = 0; kt < 4; ++kt)
#pragma unroll
        for (int g = 0; g < 4; ++g) pm = fmaxf(pm, sacc[qs][kt][g]);
      pm = fmaxf(pm, __shfl_xor(pm, 16));
      pm = fmaxf(pm, __shfl_xor(pm, 32));
      if (__any(pm > mrun[qs])) {             // exact skip: corr==1 otherwise
        const float mnew = fmaxf(mrun[qs], pm);
        const float corr = __builtin_amdgcn_exp2f(mrun[qs] - mnew);
        lsum[qs] *= corr;
#pragma unroll
        for (int dt = 0; dt < 4; ++dt) {
          oacc[qs][dt][0] *= corr; oacc[qs][dt][1] *= corr;
          oacc[qs][dt][2] *= corr; oacc[qs][dt][3] *= corr;
        }
        mrun[qs] = mnew;
      }
      float rs = 0.f;
#pragma unroll
      for (int kt = 0; kt < 4; ++kt)
#pragma unroll
        for (int g = 0; g < 4; ++g) {
          sacc[qs][kt][g] = __builtin_amdgcn_exp2f(sacc[qs][kt][g] - mrun[qs]);
          rs += sacc[qs][kt][g];
        }
      rs += __shfl_xor(rs, 16);
      rs += __shfl_xor(rs, 32);
      lsum[qs] += rs;
      // P -> per-wave-per-subtile LDS (row-major [16 q][64 k], swizzled)
#pragma unroll
      for (int kt = 0; kt < 4; ++kt) {
        u32x2 pw;
        pw[0] = cvtpk(sacc[qs][kt][0], sacc[qs][kt][1]);
        pw[1] = cvtpk(sacc[qs][kt][2], sacc[qs][kt][3]);
        *(u32x2*)&Ps[w][qs][swz(fr, kt * 16 + fp * 4)] = pw;
      }
    }
    asm volatile("s_waitcnt lgkmcnt(0)" ::: "memory");  // intra-wave cross-lane P RAW
    // P fragments per subtile
    bf16x8 pf[2][2];
#pragma unroll
    for (int qs = 0; qs < 2; ++qs) {
      pf[qs][0] = *(const bf16x8*)&Ps[w][qs][swz(fr, fp * 8)];
      pf[qs][1] = *(const bf16x8*)&Ps[w][qs][swz(fr, fp * 8 + 32)];
    }
    // O^T += V^T @ P^T ; V fragments read ONCE, shared by both q-subtiles
#pragma unroll
    for (int dt = 0; dt < 4; ++dt) {
      bf16x8 v0 = *(const bf16x8*)&Vts[cur][swz(dt * 16 + fr, fp * 8)];
      bf16x8 v1 = *(const bf16x8*)&Vts[cur][swz(dt * 16 + fr, fp * 8 + 32)];
#pragma unroll
      for (int qs = 0; qs < 2; ++qs) {
        oacc[qs][dt] = __builtin_amdgcn_mfma_f32_16x16x32_bf16(v0, pf[qs][0], oacc[qs][dt], 0, 0, 0);
        oacc[qs][dt] = __builtin_amdgcn_mfma_f32_16x16x32_bf16(v1, pf[qs][1], oacc[qs][dt], 0, 0, 0);
      }
    }
    asm volatile("s_waitcnt vmcnt(0)" ::: "memory");   // next tile landed
    __syncthreads();
  }
#undef STAGE

  // epilogue: lane holds O^T[d = dt*16 + fp*4 + g][q = q0 + qs*16 + fr]
#pragma unroll
  for (int qs = 0; qs < 2; ++qs) {
    const int q = q0 + qs * 16 + fr;
    if constexpr (SPLIT == 1) {
      const float inv = 1.f / lsum[qs];
#pragma unroll
      for (int dt = 0; dt < 4; ++dt) {
        u16x4 o;
#pragma unroll
        for (int g = 0; g < 4; ++g) o[g] = f2bf(oacc[qs][dt][g] * inv);
        *(u16x4*)(vals + (size_t)q * DMODEL + h * DK + dt * 16 + fp * 4) = o;
      }
    } else {
      float* ob = Opart + ((size_t)(s * NHEADS + h) * N_ELEC + q) * DK;
#pragma unroll
      for (int dt = 0; dt < 4; ++dt) {
        float4 o;
        o.x = oacc[qs][dt][0]; o.y = oacc[qs][dt][1];
        o.z = oacc[qs][dt][2]; o.w = oacc[qs][dt][3];
        *(float4*)(ob + dt * 16 + fp * 4) = o;
      }
      if (fp == 0) ML[(size_t)(s * NHEADS + h) * N_ELEC + q] = make_float2(mrun[qs], lsum[qs]);
    }
  }
}

// ---------- combine the 2 KV-splits ----------
__global__ __launch_bounds__(256) void combine(
    const float* __restrict__ Opart, const float2* __restrict__ ML,
    ushort* __restrict__ vals)
{
  const int rid = blockIdx.x * 4 + (threadIdx.x >> 6);  // h*4096 + q
  const int d = threadIdx.x & 63;
  const int hh = rid >> 12, qq = rid & 4095;
  const size_t base = (size_t)rid * DK + d;
  const size_t sstride = (size_t)NHEADS * N_ELEC * DK;
  float2 ml0 = ML[rid], ml1 = ML[(size_t)NHEADS * N_ELEC + rid];
  float o0 = Opart[base], o1 = Opart[sstride + base];
  float m = fmaxf(ml0.x, ml1.x);
  float c0 = __builtin_amdgcn_exp2f(ml0.x - m);
  float c1 = __builtin_amdgcn_exp2f(ml1.x - m);
  float l = c0 * ml0.y + c1 * ml1.y;
  vals[(size_t)qq * DMODEL + hh * DK + d] = f2bf((c0 * o0 + c1 * o1) / l);
}

extern "C" void kernel_launch(void* const* d_in, const int* in_sizes, int n_in,
                              void* d_out, int out_size, void* d_ws, size_t ws_size,
                              hipStream_t stream) {
  const float* hs   = (const float*)d_in[0];
  const float* hd   = (const float*)d_in[1];
  const float* qk_w = (const float*)d_in[2];
  const float* qk_b = (const float*)d_in[3];
  const float* v_w  = (const float*)d_in[4];
  const float* v_b  = (const float*)d_in[5];
  const float* o_w  = (const float*)d_in[6];
  const float* o_b  = (const float*)d_in[7];
  float* out = (float*)d_out;

  ushort* ws    = (ushort*)d_ws;
  ushort* hsb   = ws;                                   // [4096][512]
  ushort* hdb   = hsb  + (size_t)N_ELEC * DMODEL;
  ushort* wqkT  = hdb  + (size_t)N_ELEC * DMODEL;       // [1024][512]
  ushort* wvT   = wqkT + (size_t)1024 * 512;            // [512][512]
  ushort* woT   = wvT  + (size_t)512 * 512;             // [512][512]
  ushort* qbuf  = woT  + (size_t)512 * 512;             // [8][4096][64]
  ushort* kbuf  = qbuf + (size_t)NHEADS * N_ELEC * DK;  // [8][4096][64]
  ushort* vbufT = kbuf + (size_t)NHEADS * N_ELEC * DK;  // [8][64][4096]
  ushort* valsb = vbufT + (size_t)NHEADS * DK * N_ELEC; // [4096][512]
  float*  Opart = (float*)(valsb + (size_t)N_ELEC * DMODEL);   // [2][8][4096][64] f32
  float2* ML    = (float2*)(Opart + (size_t)2 * NHEADS * N_ELEC * DK);
  const size_t need = (size_t)((char*)(ML + (size_t)2 * NHEADS * N_ELEC) - (char*)d_ws);
  const bool split2 = ws_size >= need;

  dim3 blk(256);
  prep<<<dim3(2304), blk, 0, stream>>>(hs, hd, qk_w, v_w, o_w, hsb, hdb, wqkT, wvT, woT);
  proj128<0><<<dim3(32, 8), blk, 0, stream>>>(wqkT, hsb, qk_b, qbuf);   // q (scaled) + k
  proj128<1><<<dim3(32, 4), blk, 0, stream>>>(wvT,  hdb, v_b,  vbufT);

  if (split2) {
    attn<2><<<dim3(512), blk, 0, stream>>>(qbuf, kbuf, vbufT, nullptr, Opart, ML);
    combine<<<dim3(NHEADS * N_ELEC / 4), blk, 0, stream>>>(Opart, ML, valsb);
  } else {
    attn<1><<<dim3(256), blk, 0, stream>>>(qbuf, kbuf, vbufT, valsb, nullptr, nullptr);
  }

  proj128<2><<<dim3(32, 4), blk, 0, stream>>>(woT, valsb, o_b, out);
}

// Round 9
// 109.517 us; speedup vs baseline: 8.3713x; 1.0656x over previous
//
#include <hip/hip_runtime.h>
#include <math.h>

#define N_ELEC 4096
#define DMODEL 512
#define NHEADS 8
#define DK 64

typedef __attribute__((ext_vector_type(8))) short  bf16x8;
typedef __attribute__((ext_vector_type(4))) float  f32x4;
typedef __attribute__((ext_vector_type(8))) ushort u16x8;
typedef __attribute__((ext_vector_type(4))) ushort u16x4;
typedef __attribute__((ext_vector_type(2))) unsigned int u32x2;

// XOR-swizzle for [R][64] bf16 tiles (row stride 128B)
__device__ __forceinline__ int swz(int r, int c) { return r * 64 + (c ^ ((r & 7) * 8)); }

__device__ __forceinline__ ushort f2bf(float f) {
  union { float f; unsigned int u; } cv; cv.f = f;
  unsigned int u = cv.u;
  u += 0x7FFFu + ((u >> 16) & 1u);   // RNE
  return (ushort)(u >> 16);
}

__device__ __forceinline__ unsigned cvtpk(float lo, float hi) {
  unsigned r;
  asm("v_cvt_pk_bf16_f32 %0, %1, %2" : "=v"(r) : "v"(lo), "v"(hi));
  return r;
}

#define GLL16(gp, lp) __builtin_amdgcn_global_load_lds( \
    (const __attribute__((address_space(1))) void*)(gp), \
    (__attribute__((address_space(3))) void*)(lp), 16, 0, 0)

#define QK_LOG2E 0.18033688f   // 0.125 * log2(e), folded into q at projection time

// ---------- fused prep: f32->bf16 conv of hs/hd + 3 weight transposes ----------
__global__ __launch_bounds__(256) void prep(
    const float* __restrict__ hs, const float* __restrict__ hd,
    const float* __restrict__ qk_w, const float* __restrict__ v_w, const float* __restrict__ o_w,
    ushort* __restrict__ hsb, ushort* __restrict__ hdb,
    ushort* __restrict__ wqkT, ushort* __restrict__ wvT, ushort* __restrict__ woT)
{
  __shared__ float Ts[64][68];
  const int b = blockIdx.x, t = threadIdx.x;
  if (b < 2048) {
    const float* in = (b < 1024) ? hs : hd;
    ushort* outp = (b < 1024) ? hsb : hdb;
    const int idx = ((b & 1023) * 256 + t) * 8;
    float4 a = *(const float4*)(in + idx);
    float4 b2 = *(const float4*)(in + idx + 4);
    u16x8 o;
    o[0] = f2bf(a.x); o[1] = f2bf(a.y); o[2] = f2bf(a.z); o[3] = f2bf(a.w);
    o[4] = f2bf(b2.x); o[5] = f2bf(b2.y); o[6] = f2bf(b2.z); o[7] = f2bf(b2.w);
    *(u16x8*)(outp + idx) = o;
    return;
  }
  const float* in; ushort* outp; int C, tb;
  if (b < 2176)      { in = qk_w; outp = wqkT; C = 1024; tb = b - 2048; }
  else if (b < 2240) { in = v_w;  outp = wvT;  C = 512;  tb = b - 2176; }
  else               { in = o_w;  outp = woT;  C = 512;  tb = b - 2240; }
  const int ctiles = C >> 6;
  const int ct = (tb % ctiles) * 64, rt = (tb / ctiles) * 64;
  const int lr = t >> 4, lc4 = (t & 15) * 4;
#pragma unroll
  for (int rep = 0; rep < 4; ++rep) {
    const int r = lr + rep * 16;
    float4 v = *(const float4*)(in + (size_t)(rt + r) * C + ct + lc4);
    Ts[r][lc4] = v.x; Ts[r][lc4 + 1] = v.y; Ts[r][lc4 + 2] = v.z; Ts[r][lc4 + 3] = v.w;
  }
  __syncthreads();
#pragma unroll
  for (int rep = 0; rep < 4; ++rep) {
    const int c = lr + rep * 16;
    u16x4 o;
    o[0] = f2bf(Ts[lc4 + 0][c]); o[1] = f2bf(Ts[lc4 + 1][c]);
    o[2] = f2bf(Ts[lc4 + 2][c]); o[3] = f2bf(Ts[lc4 + 3][c]);
    *(u16x4*)(outp + (size_t)(ct + c) * 512 + rt + lc4) = o;
  }
}

// ---------- projection GEMM, 128x128 tile, gll-staged dbuf (round-7 validated) ----------
template<int MODE>
__global__ __launch_bounds__(256) void proj128(
    const ushort* __restrict__ Wt, const ushort* __restrict__ Act,
    const float* __restrict__ bias, void* __restrict__ outp)
{
  __shared__ ushort At[2][128 * 64];
  __shared__ ushort Bt[2][128 * 64];
  const int mt = blockIdx.x, nt = blockIdx.y;
  const int t = threadIdx.x, w = t >> 6, lane = t & 63;
  const int fr = lane & 15, fp = lane >> 4;

  const ushort* rowsA = (MODE == 1) ? Act + (size_t)mt * 128 * 512 : Wt + (size_t)nt * 128 * 512;
  const ushort* rowsB = (MODE == 1) ? Wt + (size_t)nt * 128 * 512 : Act + (size_t)mt * 128 * 512;

#define STAGEP(buf, k0) do { \
  _Pragma("unroll") \
  for (int rep = 0; rep < 4; ++rep) { \
    const int cid = rep * 256 + t; \
    const int row_ = cid >> 3; \
    const int sc = ((cid & 7) ^ (row_ & 7)) * 8; \
    GLL16(rowsA + (size_t)row_ * 512 + (k0) + sc, &At[buf][(rep * 256 + w * 64) * 8]); \
    GLL16(rowsB + (size_t)row_ * 512 + (k0) + sc, &Bt[buf][(rep * 256 + w * 64) * 8]); \
  } \
} while (0)

  const int rbase = (w >> 1) * 64;
  const int cbase = (w & 1) * 64;

  f32x4 acc[16];
#pragma unroll
  for (int i = 0; i < 16; ++i) acc[i] = (f32x4){0.f, 0.f, 0.f, 0.f};

  STAGEP(0, 0);
  asm volatile("s_waitcnt vmcnt(0)" ::: "memory");
  __syncthreads();

  for (int it = 0; it < 8; ++it) {
    const int cur = it & 1;
    if (it < 7) STAGEP(cur ^ 1, (it + 1) * 64);
#pragma unroll
    for (int kh = 0; kh < 2; ++kh) {
      bf16x8 af[4], bf[4];
#pragma unroll
      for (int i = 0; i < 4; ++i) {
        af[i] = *(const bf16x8*)&At[cur][swz(rbase + i * 16 + fr, kh * 32 + fp * 8)];
        bf[i] = *(const bf16x8*)&Bt[cur][swz(cbase + i * 16 + fr, kh * 32 + fp * 8)];
      }
#pragma unroll
      for (int i = 0; i < 4; ++i)
#pragma unroll
        for (int j = 0; j < 4; ++j)
          acc[i * 4 + j] = __builtin_amdgcn_mfma_f32_16x16x32_bf16(af[i], bf[j], acc[i * 4 + j], 0, 0, 0);
    }
    asm volatile("s_waitcnt vmcnt(0)" ::: "memory");
    __syncthreads();
  }
#undef STAGEP

  if (MODE == 0) {
    ushort* out = (ushort*)outp;
#pragma unroll
    for (int i = 0; i < 4; ++i) {
      const int nb = nt * 128 + rbase + i * 16 + fp * 4;
      const float scale = (nb < 512) ? QK_LOG2E : 1.0f;
      const float4 bb = *(const float4*)(bias + nb);
      const int h = nb >> 6, d0 = nb & 63;
#pragma unroll
      for (int j = 0; j < 4; ++j) {
        const int m = mt * 128 + cbase + j * 16 + fr;
        const f32x4 a = acc[i * 4 + j];
        u16x4 o;
        o[0] = f2bf((a[0] + bb.x) * scale); o[1] = f2bf((a[1] + bb.y) * scale);
        o[2] = f2bf((a[2] + bb.z) * scale); o[3] = f2bf((a[3] + bb.w) * scale);
        *(u16x4*)(out + (size_t)h * N_ELEC * DK + (size_t)m * DK + d0) = o;
      }
    }
  } else if (MODE == 1) {
    ushort* out = (ushort*)outp;
#pragma unroll
    for (int j = 0; j < 4; ++j) {
      const int n = nt * 128 + cbase + j * 16 + fr;
      const float bb = bias[n];
      const int h = n >> 6, dd = n & 63;
#pragma unroll
      for (int i = 0; i < 4; ++i) {
        const int m0 = mt * 128 + rbase + i * 16 + fp * 4;
        const f32x4 a = acc[i * 4 + j];
        u16x4 o;
        o[0] = f2bf(a[0] + bb); o[1] = f2bf(a[1] + bb);
        o[2] = f2bf(a[2] + bb); o[3] = f2bf(a[3] + bb);
        *(u16x4*)(out + (size_t)h * DK * N_ELEC + (size_t)dd * N_ELEC + m0) = o;
      }
    }
  } else {
    float* out = (float*)outp;
#pragma unroll
    for (int i = 0; i < 4; ++i) {
      const int n0 = nt * 128 + rbase + i * 16 + fp * 4;
      const float4 bb = *(const float4*)(bias + n0);
#pragma unroll
      for (int j = 0; j < 4; ++j) {
        const int m = mt * 128 + cbase + j * 16 + fr;
        const f32x4 a = acc[i * 4 + j];
        float4 o;
        o.x = a[0] + bb.x; o.y = a[1] + bb.y; o.z = a[2] + bb.z; o.w = a[3] + bb.w;
        *(float4*)(out + (size_t)m * DMODEL + n0) = o;
      }
    }
  }
}

// ---------- flash attention: QBLK=128, single-Ps, sequential q-subtiles ----------
// LDS 40 KB -> 4 blocks/CU; SPLIT=4 -> grid 1024 = 4 resident blocks/CU.
template<int SPLIT>
__global__ __launch_bounds__(256, 4) void attn(
    const ushort* __restrict__ qb, const ushort* __restrict__ kb,
    const ushort* __restrict__ vtb, ushort* __restrict__ vals,
    float* __restrict__ Opart, float2* __restrict__ ML)
{
  __shared__ ushort Ks[2][64 * 64], Vts[2][64 * 64];
  __shared__ ushort Ps[4][16 * 64];          // one 16x64 P buffer per wave, reused per subtile
  const int bid = blockIdx.x;
  const int h = bid & 7, qt = (bid >> 3) & 31, s = bid >> 8;
  const int t = threadIdx.x, w = t >> 6, lane = t & 63;
  const int fr = lane & 15, fp = lane >> 4;
  const int KCH = N_ELEC / SPLIT;

  const ushort* kp = kb  + (size_t)h * N_ELEC * DK + (size_t)s * KCH * DK;
  const ushort* vp = vtb + (size_t)h * DK * N_ELEC + (size_t)s * KCH;
  const int q0 = qt * 128 + w * 32;

  bf16x8 qf[2][2];
#pragma unroll
  for (int qs = 0; qs < 2; ++qs) {
    const ushort* qrow = qb + (size_t)h * N_ELEC * DK + (size_t)(q0 + qs * 16 + fr) * DK + fp * 8;
    qf[qs][0] = *(const bf16x8*)(qrow);
    qf[qs][1] = *(const bf16x8*)(qrow + 32);
  }

  const int srow = lane >> 3;
  const int schunk = ((lane & 7) ^ srow) * 8;

#define STAGE(buf, j0) do { \
  _Pragma("unroll") \
  for (int p = 0; p < 2; ++p) { \
    const int rr = (w * 2 + p) * 8 + srow; \
    GLL16(kp + (size_t)((j0) + rr) * DK + schunk, &Ks[buf][(w * 2 + p) * 512]); \
    GLL16(vp + (size_t)rr * N_ELEC + (j0) + schunk, &Vts[buf][(w * 2 + p) * 512]); \
  } \
} while (0)

  float mrun[2] = {-INFINITY, -INFINITY}, lsum[2] = {0.f, 0.f};
  f32x4 oacc[2][4];
#pragma unroll
  for (int qs = 0; qs < 2; ++qs)
#pragma unroll
    for (int dt = 0; dt < 4; ++dt) oacc[qs][dt] = (f32x4){0.f, 0.f, 0.f, 0.f};

  STAGE(0, 0);
  asm volatile("s_waitcnt vmcnt(0)" ::: "memory");
  __syncthreads();

  for (int it = 0; it < KCH / 64; ++it) {
    const int cur = it & 1;
    if ((it + 1) * 64 < KCH) STAGE(cur ^ 1, (it + 1) * 64);

    // S^T = K @ Q^T for both subtiles (K fragments read once, transient)
    f32x4 sacc[2][4];
    __builtin_amdgcn_s_setprio(1);
#pragma unroll
    for (int kt = 0; kt < 4; ++kt) {
      bf16x8 ka0 = *(const bf16x8*)&Ks[cur][swz(kt * 16 + fr, fp * 8)];
      bf16x8 ka1 = *(const bf16x8*)&Ks[cur][swz(kt * 16 + fr, fp * 8 + 32)];
#pragma unroll
      for (int qs = 0; qs < 2; ++qs) {
        f32x4 z = {0.f, 0.f, 0.f, 0.f};
        z = __builtin_amdgcn_mfma_f32_16x16x32_bf16(ka0, qf[qs][0], z, 0, 0, 0);
        sacc[qs][kt] = __builtin_amdgcn_mfma_f32_16x16x32_bf16(ka1, qf[qs][1], z, 0, 0, 0);
      }
    }
    __builtin_amdgcn_s_setprio(0);

    // per-subtile: softmax -> P (single LDS buffer) -> PV
#pragma unroll
    for (int qs = 0; qs < 2; ++qs) {
      float pm = -INFINITY;
#pragma unroll
      for (int kt = 0; kt < 4; ++kt)
#pragma unroll
        for (int g = 0; g < 4; ++g) pm = fmaxf(pm, sacc[qs][kt][g]);
      pm = fmaxf(pm, __shfl_xor(pm, 16));
      pm = fmaxf(pm, __shfl_xor(pm, 32));
      if (__any(pm > mrun[qs])) {             // exact skip: corr==1 otherwise
        const float mnew = fmaxf(mrun[qs], pm);
        const float corr = __builtin_amdgcn_exp2f(mrun[qs] - mnew);
        lsum[qs] *= corr;
#pragma unroll
        for (int dt = 0; dt < 4; ++dt) {
          oacc[qs][dt][0] *= corr; oacc[qs][dt][1] *= corr;
          oacc[qs][dt][2] *= corr; oacc[qs][dt][3] *= corr;
        }
        mrun[qs] = mnew;
      }
      float rs = 0.f;
#pragma unroll
      for (int kt = 0; kt < 4; ++kt)
#pragma unroll
        for (int g = 0; g < 4; ++g) {
          sacc[qs][kt][g] = __builtin_amdgcn_exp2f(sacc[qs][kt][g] - mrun[qs]);
          rs += sacc[qs][kt][g];
        }
      rs += __shfl_xor(rs, 16);
      rs += __shfl_xor(rs, 32);
      lsum[qs] += rs;
#pragma unroll
      for (int kt = 0; kt < 4; ++kt) {
        u32x2 pw;
        pw[0] = cvtpk(sacc[qs][kt][0], sacc[qs][kt][1]);
        pw[1] = cvtpk(sacc[qs][kt][2], sacc[qs][kt][3]);
        *(u32x2*)&Ps[w][swz(fr, kt * 16 + fp * 4)] = pw;
      }
      asm volatile("s_waitcnt lgkmcnt(0)" ::: "memory");  // intra-wave cross-lane P RAW
      bf16x8 pf0 = *(const bf16x8*)&Ps[w][swz(fr, fp * 8)];
      bf16x8 pf1 = *(const bf16x8*)&Ps[w][swz(fr, fp * 8 + 32)];
      __builtin_amdgcn_s_setprio(1);
#pragma unroll
      for (int dt = 0; dt < 4; ++dt) {
        bf16x8 v0 = *(const bf16x8*)&Vts[cur][swz(dt * 16 + fr, fp * 8)];
        bf16x8 v1 = *(const bf16x8*)&Vts[cur][swz(dt * 16 + fr, fp * 8 + 32)];
        oacc[qs][dt] = __builtin_amdgcn_mfma_f32_16x16x32_bf16(v0, pf0, oacc[qs][dt], 0, 0, 0);
        oacc[qs][dt] = __builtin_amdgcn_mfma_f32_16x16x32_bf16(v1, pf1, oacc[qs][dt], 0, 0, 0);
      }
      __builtin_amdgcn_s_setprio(0);
    }
    asm volatile("s_waitcnt vmcnt(0)" ::: "memory");   // next tile landed
    __syncthreads();
  }
#undef STAGE

  // epilogue: lane holds O^T[d = dt*16 + fp*4 + g][q = q0 + qs*16 + fr]
#pragma unroll
  for (int qs = 0; qs < 2; ++qs) {
    const int q = q0 + qs * 16 + fr;
    if constexpr (SPLIT == 1) {
      const float inv = 1.f / lsum[qs];
#pragma unroll
      for (int dt = 0; dt < 4; ++dt) {
        u16x4 o;
#pragma unroll
        for (int g = 0; g < 4; ++g) o[g] = f2bf(oacc[qs][dt][g] * inv);
        *(u16x4*)(vals + (size_t)q * DMODEL + h * DK + dt * 16 + fp * 4) = o;
      }
    } else {
      float* ob = Opart + ((size_t)(s * NHEADS + h) * N_ELEC + q) * DK;
#pragma unroll
      for (int dt = 0; dt < 4; ++dt) {
        float4 o;
        o.x = oacc[qs][dt][0]; o.y = oacc[qs][dt][1];
        o.z = oacc[qs][dt][2]; o.w = oacc[qs][dt][3];
        *(float4*)(ob + dt * 16 + fp * 4) = o;
      }
      if (fp == 0) ML[(size_t)(s * NHEADS + h) * N_ELEC + q] = make_float2(mrun[qs], lsum[qs]);
    }
  }
}

// ---------- combine NS KV-splits ----------
template<int NS>
__global__ __launch_bounds__(256) void combine(
    const float* __restrict__ Opart, const float2* __restrict__ ML,
    ushort* __restrict__ vals)
{
  const int rid = blockIdx.x * 4 + (threadIdx.x >> 6);  // h*4096 + q
  const int d = threadIdx.x & 63;
  const int hh = rid >> 12, qq = rid & 4095;
  const size_t base = (size_t)rid * DK + d;
  const size_t sstride = (size_t)NHEADS * N_ELEC * DK;
  float2 mls[NS];
  float m = -INFINITY;
#pragma unroll
  for (int i = 0; i < NS; ++i) {
    mls[i] = ML[(size_t)i * NHEADS * N_ELEC + rid];
    m = fmaxf(m, mls[i].x);
  }
  float l = 0.f, o = 0.f;
#pragma unroll
  for (int i = 0; i < NS; ++i) {
    const float c = __builtin_amdgcn_exp2f(mls[i].x - m);
    l += c * mls[i].y;
    o += c * Opart[i * sstride + base];
  }
  vals[(size_t)qq * DMODEL + hh * DK + d] = f2bf(o / l);
}

extern "C" void kernel_launch(void* const* d_in, const int* in_sizes, int n_in,
                              void* d_out, int out_size, void* d_ws, size_t ws_size,
                              hipStream_t stream) {
  const float* hs   = (const float*)d_in[0];
  const float* hd   = (const float*)d_in[1];
  const float* qk_w = (const float*)d_in[2];
  const float* qk_b = (const float*)d_in[3];
  const float* v_w  = (const float*)d_in[4];
  const float* v_b  = (const float*)d_in[5];
  const float* o_w  = (const float*)d_in[6];
  const float* o_b  = (const float*)d_in[7];
  float* out = (float*)d_out;

  ushort* ws    = (ushort*)d_ws;
  ushort* hsb   = ws;                                   // [4096][512]
  ushort* hdb   = hsb  + (size_t)N_ELEC * DMODEL;
  ushort* wqkT  = hdb  + (size_t)N_ELEC * DMODEL;       // [1024][512]
  ushort* wvT   = wqkT + (size_t)1024 * 512;            // [512][512]
  ushort* woT   = wvT  + (size_t)512 * 512;             // [512][512]
  ushort* qbuf  = woT  + (size_t)512 * 512;             // [8][4096][64]
  ushort* kbuf  = qbuf + (size_t)NHEADS * N_ELEC * DK;  // [8][4096][64]
  ushort* vbufT = kbuf + (size_t)NHEADS * N_ELEC * DK;  // [8][64][4096]
  ushort* valsb = vbufT + (size_t)NHEADS * DK * N_ELEC; // [4096][512]
  float*  Opart = (float*)(valsb + (size_t)N_ELEC * DMODEL);   // [NS][8][4096][64] f32
  float2* ML4   = (float2*)(Opart + (size_t)4 * NHEADS * N_ELEC * DK);
  float2* ML2   = (float2*)(Opart + (size_t)2 * NHEADS * N_ELEC * DK);
  const size_t need4 = (size_t)((char*)(ML4 + (size_t)4 * NHEADS * N_ELEC) - (char*)d_ws);
  const size_t need2 = (size_t)((char*)(ML2 + (size_t)2 * NHEADS * N_ELEC) - (char*)d_ws);

  dim3 blk(256);
  prep<<<dim3(2304), blk, 0, stream>>>(hs, hd, qk_w, v_w, o_w, hsb, hdb, wqkT, wvT, woT);
  proj128<0><<<dim3(32, 8), blk, 0, stream>>>(wqkT, hsb, qk_b, qbuf);   // q (scaled) + k
  proj128<1><<<dim3(32, 4), blk, 0, stream>>>(wvT,  hdb, v_b,  vbufT);

  if (ws_size >= need4) {
    attn<4><<<dim3(1024), blk, 0, stream>>>(qbuf, kbuf, vbufT, nullptr, Opart, ML4);
    combine<4><<<dim3(NHEADS * N_ELEC / 4), blk, 0, stream>>>(Opart, ML4, valsb);
  } else if (ws_size >= need2) {
    attn<2><<<dim3(512), blk, 0, stream>>>(qbuf, kbuf, vbufT, nullptr, Opart, ML2);
    combine<2><<<dim3(NHEADS * N_ELEC / 4), blk, 0, stream>>>(Opart, ML2, valsb);
  } else {
    attn<1><<<dim3(256), blk, 0, stream>>>(qbuf, kbuf, vbufT, valsb, nullptr, nullptr);
  }

  proj128<2><<<dim3(32, 4), blk, 0, stream>>>(woT, valsb, o_b, out);
}